// Round 11
// baseline (153.256 us; speedup 1.0000x reference)
//
#include <hip/hip_runtime.h>
#include <hip/hip_bf16.h>
#include <stdint.h>

#define SEQ 2048
#define DIM 1024
#define HEADS 16
#define HD 64
#define NEGV (-1e9f)
#define SCALE2 0.18033688011112042f   // 0.125 * log2(e)
#define THR2 11.541560327111707f      // 8 * log2(e)

typedef __attribute__((ext_vector_type(8))) short short8;
typedef __attribute__((ext_vector_type(4))) float f32x4;

__device__ __forceinline__ unsigned short f2bf(float f) {
  __hip_bfloat16 h = __float2bfloat16(f);
  union { __hip_bfloat16 h; unsigned short u; } cv;
  cv.h = h;
  return cv.u;
}

__device__ __forceinline__ void async16(const void* g, void* l) {
  __builtin_amdgcn_global_load_lds(
      (const __attribute__((address_space(1))) unsigned int*)g,
      (__attribute__((address_space(3))) unsigned int*)l, 16, 0, 0);
}

// ---------- fp32 -> bf16 cast, float4 vectorized ----------
__global__ void cast_bf16_k(const float* __restrict__ in,
                            unsigned short* __restrict__ out, int n4) {
  int stride = gridDim.x * blockDim.x;
  for (int i = blockIdx.x * blockDim.x + threadIdx.x; i < n4; i += stride) {
    float4 v = ((const float4*)in)[i];
    ushort4 o;
    o.x = f2bf(v.x); o.y = f2bf(v.y); o.z = f2bf(v.z); o.w = f2bf(v.w);
    ((ushort4*)out)[i] = o;
  }
}

// fused 4-weight cast: blockIdx.y selects the matrix
__global__ void cast_w4_k(const float* __restrict__ w0, const float* __restrict__ w1,
                          const float* __restrict__ w2, const float* __restrict__ w3,
                          unsigned short* __restrict__ o0, unsigned short* __restrict__ o1,
                          unsigned short* __restrict__ o2, unsigned short* __restrict__ o3,
                          int n4) {
  const float* in = (blockIdx.y == 0) ? w0 : (blockIdx.y == 1) ? w1
                   : (blockIdx.y == 2) ? w2 : w3;
  unsigned short* out = (blockIdx.y == 0) ? o0 : (blockIdx.y == 1) ? o1
                       : (blockIdx.y == 2) ? o2 : o3;
  int stride = gridDim.x * blockDim.x;
  for (int i = blockIdx.x * blockDim.x + threadIdx.x; i < n4; i += stride) {
    float4 v = ((const float4*)in)[i];
    ushort4 o;
    o.x = f2bf(v.x); o.y = f2bf(v.y); o.z = f2bf(v.z); o.w = f2bf(v.w);
    ((ushort4*)out)[i] = o;
  }
}

// ---------- GEMM staging: A[128][32] + B[128][32] tiles, 16B/lane ----------
__device__ __forceinline__ void stage_ab(const unsigned short* __restrict__ A,
                                         const unsigned short* __restrict__ B,
                                         int K, int bm0, int bn0, int k0,
                                         unsigned short* As, unsigned short* Bs,
                                         int tid) {
#pragma unroll
  for (int i = 0; i < 2; ++i) {
    int e   = (i * 256 + tid) * 8;
    int row = e >> 5;
    int kk  = e & 31;
    async16(A + (size_t)(bm0 + row) * K + (size_t)(k0 + kk), As + e);
    async16(B + (size_t)(bn0 + row) * K + (size_t)(k0 + kk), Bs + e);
  }
}

// ---------- shared GEMM core: C[128x128] tile, double-buffered staging ----------
__device__ __forceinline__ void gemm_core(const unsigned short* __restrict__ A,
                                          const unsigned short* __restrict__ B,
                                          int K, int bm0, int bn0,
                                          unsigned short (*As)[128 * 32],
                                          unsigned short (*Bs)[128 * 32],
                                          f32x4 acc[4][4]) {
  const int tid  = threadIdx.x;
  const int lane = tid & 63;
  const int w    = tid >> 6;
  const int wr   = w >> 1, wc = w & 1;
  const int lrow = lane & 15, lkg = lane >> 4;

  stage_ab(A, B, K, bm0, bn0, 0, As[0], Bs[0], tid);
  __syncthreads();   // DMA(0) drained

  for (int k0 = 0; k0 < K; k0 += 32) {
    const int cur = (k0 >> 5) & 1;
    if (k0 + 32 < K)
      stage_ab(A, B, K, bm0, bn0, k0 + 32, As[cur ^ 1], Bs[cur ^ 1], tid);

    short8 af[4], bf[4];
#pragma unroll
    for (int i = 0; i < 4; ++i) {
      af[i] = *(const short8*)(As[cur] + (wr * 64 + i * 16 + lrow) * 32 + lkg * 8);
      bf[i] = *(const short8*)(Bs[cur] + (wc * 64 + i * 16 + lrow) * 32 + lkg * 8);
    }
#pragma unroll
    for (int i = 0; i < 4; ++i)
#pragma unroll
      for (int j = 0; j < 4; ++j)
        acc[i][j] = __builtin_amdgcn_mfma_f32_16x16x32_bf16(af[i], bf[j], acc[i][j], 0, 0, 0);

    __syncthreads();   // drains stage(k+1); all waves done reading buf[cur]
  }
}

// ---------- fused QKV projection ----------
__global__ __launch_bounds__(256)
void qkv_gemm_k(const unsigned short* __restrict__ xb,
                const unsigned short* __restrict__ wqb,
                const unsigned short* __restrict__ wkb,
                const unsigned short* __restrict__ wvb,
                const float* __restrict__ bq, const float* __restrict__ bk,
                const float* __restrict__ bv,
                unsigned short* __restrict__ Qb, unsigned short* __restrict__ Kb,
                unsigned short* __restrict__ Vtb) {
  __shared__ __align__(16) unsigned short As[2][128 * 32];
  __shared__ __align__(16) unsigned short Bs[2][128 * 32];
  const int z = blockIdx.z;
  const unsigned short* B = (z == 0) ? wqb : (z == 1) ? wkb : wvb;
  const float* bias       = (z == 0) ? bq  : (z == 1) ? bk  : bv;
  const int bm0 = blockIdx.y * 128, bn0 = blockIdx.x * 128;

  f32x4 acc[4][4] = {};
  gemm_core(xb, B, DIM, bm0, bn0, As, Bs, acc);

  const int lane = threadIdx.x & 63;
  const int w = threadIdx.x >> 6, wr = w >> 1, wc = w & 1;
  unsigned short* out01 = (z == 0) ? Qb : Kb;
#pragma unroll
  for (int i = 0; i < 4; ++i)
#pragma unroll
    for (int j = 0; j < 4; ++j)
#pragma unroll
      for (int r = 0; r < 4; ++r) {
        int mg = bm0 + wr * 64 + i * 16 + (lane >> 4) * 4 + r;
        int ng = bn0 + wc * 64 + j * 16 + (lane & 15);
        float v = acc[i][j][r] + bias[ng];
        int bb = mg >> 11, s = mg & 2047, h = ng >> 6, d = ng & 63;
        int bh = bb * HEADS + h;
        if (z < 2)
          out01[((size_t)bh * SEQ + s) * HD + d] = f2bf(v);   // [b,h,s,d]
        else
          Vtb[((size_t)bh * HD + d) * SEQ + s] = f2bf(v);     // [b,h,d,s]
      }
}

// ---------- output projection (fp32 out + bias) ----------
__global__ __launch_bounds__(256)
void out_gemm_k(const unsigned short* __restrict__ Ob,
                const unsigned short* __restrict__ wob,
                const float* __restrict__ bo, float* __restrict__ out) {
  __shared__ __align__(16) unsigned short As[2][128 * 32];
  __shared__ __align__(16) unsigned short Bs[2][128 * 32];
  const int bm0 = blockIdx.y * 128, bn0 = blockIdx.x * 128;

  f32x4 acc[4][4] = {};
  gemm_core(Ob, wob, DIM, bm0, bn0, As, Bs, acc);

  const int lane = threadIdx.x & 63;
  const int w = threadIdx.x >> 6, wr = w >> 1, wc = w & 1;
#pragma unroll
  for (int i = 0; i < 4; ++i)
#pragma unroll
    for (int j = 0; j < 4; ++j)
#pragma unroll
      for (int r = 0; r < 4; ++r) {
        int mg = bm0 + wr * 64 + i * 16 + (lane >> 4) * 4 + r;
        int ng = bn0 + wc * 64 + j * 16 + (lane & 15);
        out[(size_t)mg * DIM + ng] = acc[i][j][r] + bo[ng];
      }
}

// ---------- attention: K-only staging (V read direct from L2) ----------
__device__ __forceinline__ void stage_k64(const unsigned short* __restrict__ kbase,
                                          int k0, unsigned short* KsB, int tid) {
#pragma unroll
  for (int j = 0; j < 2; ++j) {
    const int c    = j * 256 + tid;   // 512 chunks of 16B: K[64][64]
    const int row  = c >> 3;
    const int colb = (c & 7) << 4;
    const int srcb = colb ^ ((row & 7) << 4);
    async16(kbase + (size_t)(k0 + row) * HD + (srcb >> 1), KsB + c * 8);
  }
}

// ---------- flash attention: single-Q block, double-buffered K, global V ----------
// grid (32 bh, 32 qbpos) x 256 threads. qb = 31-blockIdx.y, x-fastest =>
// globally longest-first (LPT). LDS = 2*8K (K) + 8K (P) = 24576 B ->
// 6 blocks/CU (24 waves). V is L2-hot (FETCH=12MB evidence) -> read V
// fragments directly from global, issued BEFORE the K-staging DMA so PV
// waits at vmcnt(2) without draining the next tile's stage.
__global__ __launch_bounds__(256)
void attn_k(const unsigned short* __restrict__ Q,
            const unsigned short* __restrict__ Kp,
            const unsigned short* __restrict__ Vt,
            const int* __restrict__ pm,
            unsigned short* __restrict__ O) {
  __shared__ __align__(16) unsigned short Ks[2][64 * 64];
  __shared__ __align__(16) unsigned short plds[4][16 * 64];

  const int tid  = threadIdx.x;
  const int lane = tid & 63;
  const int w    = tid >> 6;
  const int lc = lane & 15, lg = lane >> 4;
  const int qb = 31 - blockIdx.y;          // globally longest-first
  const int bh = blockIdx.x;
  const int b  = bh >> 4, h = bh & 15;

  const size_t base = (size_t)bh * SEQ * HD;
  const unsigned short* kbase = Kp + base;
  const unsigned short* vbase = Vt + (size_t)bh * HD * SEQ;
  const int* pmb = pm + b * SEQ;
  char* pb = (char*)&plds[w][0];
  const int swp = (lc & 7) << 4;

  const int qrow0 = qb * 64 + w * 16;
  const int qrow  = qrow0 + lc;

  short8 qa[2];
  {
    const unsigned short* qp = Q + base + (size_t)qrow * HD + lg * 8;
    qa[0] = *(const short8*)(qp);
    qa[1] = *(const short8*)(qp + 32);
  }

  f32x4 oacc[4] = {};
  float mrow = -1e30f, lsum = 0.f;

  const int nk = qb + 1;                   // 64-wide k-tiles to the diagonal

  stage_k64(kbase, 0, Ks[0], tid);

  // per-wave padding-mask scan (redundant across waves; no LDS, no extra sync)
  int ok = 1;
  for (int i = lane; i < SEQ / 4; i += 64) {
    int4 v = ((const int4*)pmb)[i];
    ok &= (v.x != 0) & (v.y != 0) & (v.z != 0) & (v.w != 0);
  }
  const bool allones = __all(ok);
  __syncthreads();   // DMA(0) drained

  for (int kt = 0; kt < nk; ++kt) {
    const int cur = kt & 1;
    const int k0 = kt * 64;

    // ---- V fragment loads from global (oldest in vmcnt queue) ----
    short8 va[8];
#pragma unroll
    for (int t = 0; t < 4; ++t)
#pragma unroll
      for (int ks = 0; ks < 2; ++ks)
        va[t * 2 + ks] = *(const short8*)(vbase + (size_t)(t * 16 + lc) * SEQ +
                                          k0 + ks * 32 + lg * 8);

    if (kt + 1 < nk)
      stage_k64(kbase, k0 + 64, Ks[cur ^ 1], tid);

    // ---- QK^T swapped: mfma(K, Q) -> lane holds S[q=qrow][k-slice] ----
    f32x4 s[4];
    const char* kbuf = (const char*)Ks[cur];
    __builtin_amdgcn_s_setprio(1);
#pragma unroll
    for (int t = 0; t < 4; ++t) {
      const int row = t * 16 + lc;
      const int swk = (row & 7) << 4;
      const char* kr = kbuf + row * 128;
      short8 kb0 = *(const short8*)(kr + ((lg * 16) ^ swk));
      short8 kb1 = *(const short8*)(kr + ((lg * 16 + 64) ^ swk));
      f32x4 z = {};
      z = __builtin_amdgcn_mfma_f32_16x16x32_bf16(kb0, qa[0], z, 0, 0, 0);
      z = __builtin_amdgcn_mfma_f32_16x16x32_bf16(kb1, qa[1], z, 0, 0, 0);
#pragma unroll
      for (int r = 0; r < 4; ++r) s[t][r] = z[r] * SCALE2;   // log2-domain
    }
    __builtin_amdgcn_s_setprio(0);

    // ---- masks: full work only if padding has zeros; else diagonal only ----
    if (!allones) {
#pragma unroll
      for (int t = 0; t < 4; ++t) {
        const int kr0 = k0 + t * 16;
        int4 pmv = *(const int4*)(pmb + kr0 + lg * 4);
#pragma unroll
        for (int r = 0; r < 4; ++r) {
          const int kidx = kr0 + lg * 4 + r;
          if (kidx > qrow || (&pmv.x)[r] == 0) s[t][r] = NEGV;
        }
      }
    } else if (kt == qb) {
#pragma unroll
      for (int t = 0; t < 4; ++t)
#pragma unroll
        for (int r = 0; r < 4; ++r) {
          const int kidx = k0 + t * 16 + lg * 4 + r;
          if (kidx > qrow) s[t][r] = NEGV;
        }
    }

    // ---- online softmax: shuffle-free common path (defer-max) ----
    float mx = -1e30f;
#pragma unroll
    for (int t = 0; t < 4; ++t)
      mx = fmaxf(mx, fmaxf(fmaxf(s[t][0], s[t][1]), fmaxf(s[t][2], s[t][3])));
    if (!__all(mx <= mrow + THR2)) {       // rare: true row max + rescale
      mx = fmaxf(mx, __shfl_xor(mx, 16, 64));
      mx = fmaxf(mx, __shfl_xor(mx, 32, 64));
      const float mnew = fmaxf(mrow, mx);
      const float sc = exp2f(mrow - mnew);
      lsum *= sc;
      mrow = mnew;
      const float s0 = __shfl(sc, lg * 4 + 0, 64);
      const float s1 = __shfl(sc, lg * 4 + 1, 64);
      const float s2 = __shfl(sc, lg * 4 + 2, 64);
      const float s3 = __shfl(sc, lg * 4 + 3, 64);
#pragma unroll
      for (int t = 0; t < 4; ++t) {
        oacc[t][0] *= s0; oacc[t][1] *= s1; oacc[t][2] *= s2; oacc[t][3] *= s3;
      }
    }
    float sum = 0.f;
#pragma unroll
    for (int t = 0; t < 4; ++t)
#pragma unroll
      for (int r = 0; r < 4; ++r) {
        const float p = exp2f(s[t][r] - mrow);
        s[t][r] = p;
        sum += p;
      }
    lsum += sum;                           // per-lane partial; reduced at end

    // ---- P -> per-wave LDS (bf16, swizzled), wave-synchronous ----
#pragma unroll
    for (int t = 0; t < 4; ++t) {
      short4 pk;
      pk.x = (short)f2bf(s[t][0]); pk.y = (short)f2bf(s[t][1]);
      pk.z = (short)f2bf(s[t][2]); pk.w = (short)f2bf(s[t][3]);
      const int colb = (t * 16 + lg * 4) * 2;
      *(short4*)(pb + lc * 128 + (colb ^ swp)) = pk;
    }
    short8 pa[2];
#pragma unroll
    for (int ks = 0; ks < 2; ++ks)
      pa[ks] = *(const short8*)(pb + lc * 128 + (((ks * 32 + lg * 8) * 2) ^ swp));

    // ---- PV: O += P @ V (V from registers; waits vmcnt(2), stage stays) ----
    __builtin_amdgcn_s_setprio(1);
#pragma unroll
    for (int t = 0; t < 4; ++t)
#pragma unroll
      for (int ks = 0; ks < 2; ++ks)
        oacc[t] = __builtin_amdgcn_mfma_f32_16x16x32_bf16(pa[ks], va[t * 2 + ks],
                                                          oacc[t], 0, 0, 0);
    __builtin_amdgcn_s_setprio(0);

    __syncthreads();   // drains stage(kt+1) DMA; all waves done with Ks[cur]
  }

  // ---- epilogue: reduce partial lsum across the 4 row-copies, store ----
  lsum += __shfl_xor(lsum, 16, 64);
  lsum += __shfl_xor(lsum, 32, 64);
  const float l0 = __shfl(lsum, lg * 4 + 0, 64);
  const float l1 = __shfl(lsum, lg * 4 + 1, 64);
  const float l2 = __shfl(lsum, lg * 4 + 2, 64);
  const float l3 = __shfl(lsum, lg * 4 + 3, 64);
  const float i0 = 1.f / l0, i1 = 1.f / l1, i2 = 1.f / l2, i3 = 1.f / l3;
#pragma unroll
  for (int t = 0; t < 4; ++t) {
    const size_t o0 = ((size_t)(b * SEQ + qrow0 + lg * 4)) * DIM + h * HD + t * 16 + lc;
    O[o0]           = f2bf(oacc[t][0] * i0);
    O[o0 + DIM]     = f2bf(oacc[t][1] * i1);
    O[o0 + 2 * DIM] = f2bf(oacc[t][2] * i2);
    O[o0 + 3 * DIM] = f2bf(oacc[t][3] * i3);
  }
}

extern "C" void kernel_launch(void* const* d_in, const int* in_sizes, int n_in,
                              void* d_out, int out_size, void* d_ws, size_t ws_size,
                              hipStream_t stream) {
  const float* x  = (const float*)d_in[0];
  const int*   pm = (const int*)d_in[1];
  const float* Wq = (const float*)d_in[3];
  const float* bq = (const float*)d_in[4];
  const float* Wk = (const float*)d_in[5];
  const float* bk = (const float*)d_in[6];
  const float* Wv = (const float*)d_in[7];
  const float* bv = (const float*)d_in[8];
  const float* Wo = (const float*)d_in[9];
  const float* bo = (const float*)d_in[10];

  const size_t NX = (size_t)4096 * 1024;
  const size_t NW = (size_t)1024 * 1024;

  unsigned short* ws  = (unsigned short*)d_ws;
  unsigned short* xb  = ws;
  unsigned short* wqb = xb + NX;
  unsigned short* wkb = wqb + NW;
  unsigned short* wvb = wkb + NW;
  unsigned short* wob = wvb + NW;
  unsigned short* Qb  = wob + NW;
  unsigned short* Kb  = Qb + NX;
  unsigned short* Vtb = Kb + NX;
  unsigned short* Ob  = xb;   // alias: x no longer needed after QKV GEMM

  cast_bf16_k<<<dim3(2048), dim3(256), 0, stream>>>(x, xb, (int)(NX / 4));
  cast_w4_k<<<dim3(512, 4), dim3(256), 0, stream>>>(Wq, Wk, Wv, Wo,
                                                    wqb, wkb, wvb, wob,
                                                    (int)(NW / 4));

  qkv_gemm_k<<<dim3(8, 32, 3), dim3(256), 0, stream>>>(xb, wqb, wkb, wvb,
                                                       bq, bk, bv, Qb, Kb, Vtb);

  attn_k<<<dim3(32, 32), dim3(256), 0, stream>>>(Qb, Kb, Vtb, pm, Ob);

  out_gemm_k<<<dim3(8, 32), dim3(256), 0, stream>>>(Ob, wob, bo, (float*)d_out);
}

// Round 12
// 131.742 us; speedup vs baseline: 1.1633x; 1.1633x over previous
//
#include <hip/hip_runtime.h>
#include <hip/hip_bf16.h>
#include <stdint.h>

#define SEQ 2048
#define DIM 1024
#define HEADS 16
#define HD 64
#define NEGV (-1e9f)
#define SCALE2 0.18033688011112042f   // 0.125 * log2(e)
#define THR2 11.541560327111707f      // 8 * log2(e)

typedef __attribute__((ext_vector_type(8))) short short8;
typedef __attribute__((ext_vector_type(4))) float f32x4;

__device__ __forceinline__ unsigned short f2bf(float f) {
  __hip_bfloat16 h = __float2bfloat16(f);
  union { __hip_bfloat16 h; unsigned short u; } cv;
  cv.h = h;
  return cv.u;
}

__device__ __forceinline__ void async16(const void* g, void* l) {
  __builtin_amdgcn_global_load_lds(
      (const __attribute__((address_space(1))) unsigned int*)g,
      (__attribute__((address_space(3))) unsigned int*)l, 16, 0, 0);
}

// ---------- fp32 -> bf16 cast, float4 vectorized ----------
__global__ void cast_bf16_k(const float* __restrict__ in,
                            unsigned short* __restrict__ out, int n4) {
  int stride = gridDim.x * blockDim.x;
  for (int i = blockIdx.x * blockDim.x + threadIdx.x; i < n4; i += stride) {
    float4 v = ((const float4*)in)[i];
    ushort4 o;
    o.x = f2bf(v.x); o.y = f2bf(v.y); o.z = f2bf(v.z); o.w = f2bf(v.w);
    ((ushort4*)out)[i] = o;
  }
}

// fused 4-weight cast: blockIdx.y selects the matrix
__global__ void cast_w4_k(const float* __restrict__ w0, const float* __restrict__ w1,
                          const float* __restrict__ w2, const float* __restrict__ w3,
                          unsigned short* __restrict__ o0, unsigned short* __restrict__ o1,
                          unsigned short* __restrict__ o2, unsigned short* __restrict__ o3,
                          int n4) {
  const float* in = (blockIdx.y == 0) ? w0 : (blockIdx.y == 1) ? w1
                   : (blockIdx.y == 2) ? w2 : w3;
  unsigned short* out = (blockIdx.y == 0) ? o0 : (blockIdx.y == 1) ? o1
                       : (blockIdx.y == 2) ? o2 : o3;
  int stride = gridDim.x * blockDim.x;
  for (int i = blockIdx.x * blockDim.x + threadIdx.x; i < n4; i += stride) {
    float4 v = ((const float4*)in)[i];
    ushort4 o;
    o.x = f2bf(v.x); o.y = f2bf(v.y); o.z = f2bf(v.z); o.w = f2bf(v.w);
    ((ushort4*)out)[i] = o;
  }
}

// ---------- GEMM staging: A[128][32] + B[128][32] tiles, 16B/lane ----------
__device__ __forceinline__ void stage_ab(const unsigned short* __restrict__ A,
                                         const unsigned short* __restrict__ B,
                                         int K, int bm0, int bn0, int k0,
                                         unsigned short* As, unsigned short* Bs,
                                         int tid) {
#pragma unroll
  for (int i = 0; i < 2; ++i) {
    int e   = (i * 256 + tid) * 8;
    int row = e >> 5;
    int kk  = e & 31;
    async16(A + (size_t)(bm0 + row) * K + (size_t)(k0 + kk), As + e);
    async16(B + (size_t)(bn0 + row) * K + (size_t)(k0 + kk), Bs + e);
  }
}

// ---------- shared GEMM core: C[128x128] tile, double-buffered staging ----------
__device__ __forceinline__ void gemm_core(const unsigned short* __restrict__ A,
                                          const unsigned short* __restrict__ B,
                                          int K, int bm0, int bn0,
                                          unsigned short (*As)[128 * 32],
                                          unsigned short (*Bs)[128 * 32],
                                          f32x4 acc[4][4]) {
  const int tid  = threadIdx.x;
  const int lane = tid & 63;
  const int w    = tid >> 6;
  const int wr   = w >> 1, wc = w & 1;
  const int lrow = lane & 15, lkg = lane >> 4;

  stage_ab(A, B, K, bm0, bn0, 0, As[0], Bs[0], tid);
  __syncthreads();   // DMA(0) drained

  for (int k0 = 0; k0 < K; k0 += 32) {
    const int cur = (k0 >> 5) & 1;
    if (k0 + 32 < K)
      stage_ab(A, B, K, bm0, bn0, k0 + 32, As[cur ^ 1], Bs[cur ^ 1], tid);

    short8 af[4], bf[4];
#pragma unroll
    for (int i = 0; i < 4; ++i) {
      af[i] = *(const short8*)(As[cur] + (wr * 64 + i * 16 + lrow) * 32 + lkg * 8);
      bf[i] = *(const short8*)(Bs[cur] + (wc * 64 + i * 16 + lrow) * 32 + lkg * 8);
    }
#pragma unroll
    for (int i = 0; i < 4; ++i)
#pragma unroll
      for (int j = 0; j < 4; ++j)
        acc[i][j] = __builtin_amdgcn_mfma_f32_16x16x32_bf16(af[i], bf[j], acc[i][j], 0, 0, 0);

    __syncthreads();   // drains stage(k+1); all waves done reading buf[cur]
  }
}

// ---------- fused QKV projection ----------
__global__ __launch_bounds__(256)
void qkv_gemm_k(const unsigned short* __restrict__ xb,
                const unsigned short* __restrict__ wqb,
                const unsigned short* __restrict__ wkb,
                const unsigned short* __restrict__ wvb,
                const float* __restrict__ bq, const float* __restrict__ bk,
                const float* __restrict__ bv,
                unsigned short* __restrict__ Qb, unsigned short* __restrict__ Kb,
                unsigned short* __restrict__ Vtb) {
  __shared__ __align__(16) unsigned short As[2][128 * 32];
  __shared__ __align__(16) unsigned short Bs[2][128 * 32];
  const int z = blockIdx.z;
  const unsigned short* B = (z == 0) ? wqb : (z == 1) ? wkb : wvb;
  const float* bias       = (z == 0) ? bq  : (z == 1) ? bk  : bv;
  const int bm0 = blockIdx.y * 128, bn0 = blockIdx.x * 128;

  f32x4 acc[4][4] = {};
  gemm_core(xb, B, DIM, bm0, bn0, As, Bs, acc);

  const int lane = threadIdx.x & 63;
  const int w = threadIdx.x >> 6, wr = w >> 1, wc = w & 1;
  unsigned short* out01 = (z == 0) ? Qb : Kb;
#pragma unroll
  for (int i = 0; i < 4; ++i)
#pragma unroll
    for (int j = 0; j < 4; ++j)
#pragma unroll
      for (int r = 0; r < 4; ++r) {
        int mg = bm0 + wr * 64 + i * 16 + (lane >> 4) * 4 + r;
        int ng = bn0 + wc * 64 + j * 16 + (lane & 15);
        float v = acc[i][j][r] + bias[ng];
        int bb = mg >> 11, s = mg & 2047, h = ng >> 6, d = ng & 63;
        int bh = bb * HEADS + h;
        if (z < 2)
          out01[((size_t)bh * SEQ + s) * HD + d] = f2bf(v);   // [b,h,s,d]
        else
          Vtb[((size_t)bh * HD + d) * SEQ + s] = f2bf(v);     // [b,h,d,s]
      }
}

// ---------- output projection (fp32 out + bias) ----------
__global__ __launch_bounds__(256)
void out_gemm_k(const unsigned short* __restrict__ Ob,
                const unsigned short* __restrict__ wob,
                const float* __restrict__ bo, float* __restrict__ out) {
  __shared__ __align__(16) unsigned short As[2][128 * 32];
  __shared__ __align__(16) unsigned short Bs[2][128 * 32];
  const int bm0 = blockIdx.y * 128, bn0 = blockIdx.x * 128;

  f32x4 acc[4][4] = {};
  gemm_core(Ob, wob, DIM, bm0, bn0, As, Bs, acc);

  const int lane = threadIdx.x & 63;
  const int w = threadIdx.x >> 6, wr = w >> 1, wc = w & 1;
#pragma unroll
  for (int i = 0; i < 4; ++i)
#pragma unroll
    for (int j = 0; j < 4; ++j)
#pragma unroll
      for (int r = 0; r < 4; ++r) {
        int mg = bm0 + wr * 64 + i * 16 + (lane >> 4) * 4 + r;
        int ng = bn0 + wc * 64 + j * 16 + (lane & 15);
        out[(size_t)mg * DIM + ng] = acc[i][j][r] + bo[ng];
      }
}

// ---------- attention: KVBLK=64 staging, swizzled source ----------
__device__ __forceinline__ void stage_kv64(const unsigned short* __restrict__ kbase,
                                           const unsigned short* __restrict__ vbase,
                                           int k0, unsigned short* KsB,
                                           unsigned short* VsB, int tid) {
#pragma unroll
  for (int j = 0; j < 2; ++j) {
    const int c    = j * 256 + tid;   // 512 chunks of 16B: K[64][64]
    const int row  = c >> 3;
    const int colb = (c & 7) << 4;
    const int srcb = colb ^ ((row & 7) << 4);
    async16(kbase + (size_t)(k0 + row) * HD + (srcb >> 1), KsB + c * 8);
  }
#pragma unroll
  for (int j = 0; j < 2; ++j) {
    const int c    = j * 256 + tid;   // V[64 d][64 k]
    const int d    = c >> 3;
    const int colb = (c & 7) << 4;
    const int srcb = colb ^ ((d & 7) << 4);
    async16(vbase + (size_t)d * SEQ + k0 + (srcb >> 1), VsB + c * 8);
  }
}

// ---------- flash attention: single-Q block, double-buffered KVBLK=64 ----------
// grid (32 bh, 32 y) x 256 threads. qb(y) chosen so each CU's stride-256
// resident set {y, y+8, y+16, y+24} has constant total work (66 tiles):
// r=y&7, m=y>>3 -> qb = {r, 15-r, 16+r, 31-r}[m]. All 1024 blocks are
// co-resident (LDS 40960 -> exactly 4 blocks/CU), so per-CU balance, not
// dispatch order, sets the makespan.
__global__ __launch_bounds__(256)
void attn_k(const unsigned short* __restrict__ Q,
            const unsigned short* __restrict__ Kp,
            const unsigned short* __restrict__ Vt,
            const int* __restrict__ pm,
            unsigned short* __restrict__ O) {
  __shared__ __align__(16) unsigned short Ks[2][64 * 64];
  __shared__ __align__(16) unsigned short Vs[2][64 * 64];
  __shared__ __align__(16) unsigned short plds[4][16 * 64];

  const int tid  = threadIdx.x;
  const int lane = tid & 63;
  const int w    = tid >> 6;
  const int lc = lane & 15, lg = lane >> 4;
  const int y = blockIdx.y;
  const int r_ = y & 7, m_ = y >> 3;
  const int qb = (m_ == 0) ? r_ : (m_ == 1) ? (15 - r_)
               : (m_ == 2) ? (16 + r_) : (31 - r_);
  const int bh = blockIdx.x;
  const int b  = bh >> 4, h = bh & 15;

  const size_t base = (size_t)bh * SEQ * HD;
  const unsigned short* kbase = Kp + base;
  const unsigned short* vbase = Vt + (size_t)bh * HD * SEQ;
  const int* pmb = pm + b * SEQ;
  char* pb = (char*)&plds[w][0];
  const int swp = (lc & 7) << 4;

  const int qrow0 = qb * 64 + w * 16;
  const int qrow  = qrow0 + lc;

  short8 qa[2];
  {
    const unsigned short* qp = Q + base + (size_t)qrow * HD + lg * 8;
    qa[0] = *(const short8*)(qp);
    qa[1] = *(const short8*)(qp + 32);
  }

  f32x4 oacc[4] = {};
  float mrow = -1e30f, lsum = 0.f;

  const int nk = qb + 1;                   // 64-wide k-tiles to the diagonal

  stage_kv64(kbase, vbase, 0, Ks[0], Vs[0], tid);

  // per-wave padding-mask scan (no LDS flag; overlaps DMA(0))
  int ok = 1;
  for (int i = lane; i < SEQ / 4; i += 64) {
    int4 v = ((const int4*)pmb)[i];
    ok &= (v.x != 0) & (v.y != 0) & (v.z != 0) & (v.w != 0);
  }
  const bool allones = __all(ok);
  __syncthreads();   // DMA(0) drained

  for (int kt = 0; kt < nk; ++kt) {
    const int cur = kt & 1;
    const int k0 = kt * 64;
    if (kt + 1 < nk)
      stage_kv64(kbase, vbase, k0 + 64, Ks[cur ^ 1], Vs[cur ^ 1], tid);

    // ---- QK^T swapped: mfma(K, Q) -> lane holds S[q=qrow][k-slice] ----
    f32x4 s[4];
    const char* kbuf = (const char*)Ks[cur];
    __builtin_amdgcn_s_setprio(1);
#pragma unroll
    for (int t = 0; t < 4; ++t) {
      const int row = t * 16 + lc;
      const int swk = (row & 7) << 4;
      const char* kr = kbuf + row * 128;
      short8 kb0 = *(const short8*)(kr + ((lg * 16) ^ swk));
      short8 kb1 = *(const short8*)(kr + ((lg * 16 + 64) ^ swk));
      f32x4 z = {};
      z = __builtin_amdgcn_mfma_f32_16x16x32_bf16(kb0, qa[0], z, 0, 0, 0);
      z = __builtin_amdgcn_mfma_f32_16x16x32_bf16(kb1, qa[1], z, 0, 0, 0);
#pragma unroll
      for (int r = 0; r < 4; ++r) s[t][r] = z[r] * SCALE2;   // log2-domain
    }
    __builtin_amdgcn_s_setprio(0);

    // ---- masks: full work only if padding has zeros; else diagonal only ----
    if (!allones) {
#pragma unroll
      for (int t = 0; t < 4; ++t) {
        const int kr0 = k0 + t * 16;
        int4 pmv = *(const int4*)(pmb + kr0 + lg * 4);
#pragma unroll
        for (int r = 0; r < 4; ++r) {
          const int kidx = kr0 + lg * 4 + r;
          if (kidx > qrow || (&pmv.x)[r] == 0) s[t][r] = NEGV;
        }
      }
    } else if (kt == qb) {
#pragma unroll
      for (int t = 0; t < 4; ++t)
#pragma unroll
        for (int r = 0; r < 4; ++r) {
          const int kidx = k0 + t * 16 + lg * 4 + r;
          if (kidx > qrow) s[t][r] = NEGV;
        }
    }

    // ---- online softmax: shuffle-free common path (defer-max) ----
    float mx = -1e30f;
#pragma unroll
    for (int t = 0; t < 4; ++t)
      mx = fmaxf(mx, fmaxf(fmaxf(s[t][0], s[t][1]), fmaxf(s[t][2], s[t][3])));
    if (!__all(mx <= mrow + THR2)) {       // rare: true row max + rescale
      mx = fmaxf(mx, __shfl_xor(mx, 16, 64));
      mx = fmaxf(mx, __shfl_xor(mx, 32, 64));
      const float mnew = fmaxf(mrow, mx);
      const float sc = exp2f(mrow - mnew);
      lsum *= sc;
      mrow = mnew;
      const float s0 = __shfl(sc, lg * 4 + 0, 64);
      const float s1 = __shfl(sc, lg * 4 + 1, 64);
      const float s2 = __shfl(sc, lg * 4 + 2, 64);
      const float s3 = __shfl(sc, lg * 4 + 3, 64);
#pragma unroll
      for (int t = 0; t < 4; ++t) {
        oacc[t][0] *= s0; oacc[t][1] *= s1; oacc[t][2] *= s2; oacc[t][3] *= s3;
      }
    }
    float sum = 0.f;
#pragma unroll
    for (int t = 0; t < 4; ++t)
#pragma unroll
      for (int r = 0; r < 4; ++r) {
        const float p = exp2f(s[t][r] - mrow);
        s[t][r] = p;
        sum += p;
      }
    lsum += sum;                           // per-lane partial; reduced at end

    // ---- P -> per-wave LDS (bf16, swizzled), wave-synchronous ----
#pragma unroll
    for (int t = 0; t < 4; ++t) {
      short4 pk;
      pk.x = (short)f2bf(s[t][0]); pk.y = (short)f2bf(s[t][1]);
      pk.z = (short)f2bf(s[t][2]); pk.w = (short)f2bf(s[t][3]);
      const int colb = (t * 16 + lg * 4) * 2;
      *(short4*)(pb + lc * 128 + (colb ^ swp)) = pk;
    }
    short8 pa[2];
#pragma unroll
    for (int ks = 0; ks < 2; ++ks)
      pa[ks] = *(const short8*)(pb + lc * 128 + (((ks * 32 + lg * 8) * 2) ^ swp));

    // ---- PV: O += P @ V, V fragments from swizzled LDS ----
    const char* vbuf = (const char*)Vs[cur];
    __builtin_amdgcn_s_setprio(1);
#pragma unroll
    for (int t = 0; t < 4; ++t) {
      const int d = t * 16 + lc;
      const int swv = (d & 7) << 4;
      const char* vr = vbuf + d * 128;
#pragma unroll
      for (int ks = 0; ks < 2; ++ks) {
        short8 vv = *(const short8*)(vr + ((ks * 64 + lg * 16) ^ swv));
        oacc[t] = __builtin_amdgcn_mfma_f32_16x16x32_bf16(pa[ks], vv, oacc[t], 0, 0, 0);
      }
    }
    __builtin_amdgcn_s_setprio(0);

    __syncthreads();   // drains stage(kt+1) DMA; all waves done with buf[cur]
  }

  // ---- epilogue: reduce partial lsum across the 4 row-copies, store ----
  lsum += __shfl_xor(lsum, 16, 64);
  lsum += __shfl_xor(lsum, 32, 64);
  const float l0 = __shfl(lsum, lg * 4 + 0, 64);
  const float l1 = __shfl(lsum, lg * 4 + 1, 64);
  const float l2 = __shfl(lsum, lg * 4 + 2, 64);
  const float l3 = __shfl(lsum, lg * 4 + 3, 64);
  const float i0 = 1.f / l0, i1 = 1.f / l1, i2 = 1.f / l2, i3 = 1.f / l3;
#pragma unroll
  for (int t = 0; t < 4; ++t) {
    const size_t o0 = ((size_t)(b * SEQ + qrow0 + lg * 4)) * DIM + h * HD + t * 16 + lc;
    O[o0]           = f2bf(oacc[t][0] * i0);
    O[o0 + DIM]     = f2bf(oacc[t][1] * i1);
    O[o0 + 2 * DIM] = f2bf(oacc[t][2] * i2);
    O[o0 + 3 * DIM] = f2bf(oacc[t][3] * i3);
  }
}

extern "C" void kernel_launch(void* const* d_in, const int* in_sizes, int n_in,
                              void* d_out, int out_size, void* d_ws, size_t ws_size,
                              hipStream_t stream) {
  const float* x  = (const float*)d_in[0];
  const int*   pm = (const int*)d_in[1];
  const float* Wq = (const float*)d_in[3];
  const float* bq = (const float*)d_in[4];
  const float* Wk = (const float*)d_in[5];
  const float* bk = (const float*)d_in[6];
  const float* Wv = (const float*)d_in[7];
  const float* bv = (const float*)d_in[8];
  const float* Wo = (const float*)d_in[9];
  const float* bo = (const float*)d_in[10];

  const size_t NX = (size_t)4096 * 1024;
  const size_t NW = (size_t)1024 * 1024;

  unsigned short* ws  = (unsigned short*)d_ws;
  unsigned short* xb  = ws;
  unsigned short* wqb = xb + NX;
  unsigned short* wkb = wqb + NW;
  unsigned short* wvb = wkb + NW;
  unsigned short* wob = wvb + NW;
  unsigned short* Qb  = wob + NW;
  unsigned short* Kb  = Qb + NX;
  unsigned short* Vtb = Kb + NX;
  unsigned short* Ob  = xb;   // alias: x no longer needed after QKV GEMM

  cast_bf16_k<<<dim3(2048), dim3(256), 0, stream>>>(x, xb, (int)(NX / 4));
  cast_w4_k<<<dim3(512, 4), dim3(256), 0, stream>>>(Wq, Wk, Wv, Wo,
                                                    wqb, wkb, wvb, wob,
                                                    (int)(NW / 4));

  qkv_gemm_k<<<dim3(8, 32, 3), dim3(256), 0, stream>>>(xb, wqb, wkb, wvb,
                                                       bq, bk, bv, Qb, Kb, Vtb);

  attn_k<<<dim3(32, 32), dim3(256), 0, stream>>>(Qb, Kb, Vtb, pm, Ob);

  out_gemm_k<<<dim3(8, 32), dim3(256), 0, stream>>>(Ob, wob, bo, (float*)d_out);
}

// Round 13
// 131.449 us; speedup vs baseline: 1.1659x; 1.0022x over previous
//
#include <hip/hip_runtime.h>
#include <hip/hip_bf16.h>
#include <stdint.h>

#define SEQ 2048
#define DIM 1024
#define HEADS 16
#define HD 64
#define NEGV (-1e9f)
#define SCALE2 0.18033688011112042f   // 0.125 * log2(e)
#define THR2 11.541560327111707f      // 8 * log2(e)

typedef __attribute__((ext_vector_type(8))) short short8;
typedef __attribute__((ext_vector_type(4))) float f32x4;

__device__ __forceinline__ unsigned short f2bf(float f) {
  __hip_bfloat16 h = __float2bfloat16(f);
  union { __hip_bfloat16 h; unsigned short u; } cv;
  cv.h = h;
  return cv.u;
}

__device__ __forceinline__ void async16(const void* g, void* l) {
  __builtin_amdgcn_global_load_lds(
      (const __attribute__((address_space(1))) unsigned int*)g,
      (__attribute__((address_space(3))) unsigned int*)l, 16, 0, 0);
}

// ---------- merged fp32 -> bf16 cast: y=0 -> x, y=1..4 -> weights ----------
__global__ void cast_all_k(const float* __restrict__ x,
                           const float* __restrict__ w0, const float* __restrict__ w1,
                           const float* __restrict__ w2, const float* __restrict__ w3,
                           unsigned short* __restrict__ xo,
                           unsigned short* __restrict__ o0, unsigned short* __restrict__ o1,
                           unsigned short* __restrict__ o2, unsigned short* __restrict__ o3,
                           int nx4, int nw4) {
  const int seg = blockIdx.y;
  const float* in = (seg == 0) ? x : (seg == 1) ? w0 : (seg == 2) ? w1
                   : (seg == 3) ? w2 : w3;
  unsigned short* out = (seg == 0) ? xo : (seg == 1) ? o0 : (seg == 2) ? o1
                       : (seg == 3) ? o2 : o3;
  const int n4 = (seg == 0) ? nx4 : nw4;
  int stride = gridDim.x * blockDim.x;
  for (int i = blockIdx.x * blockDim.x + threadIdx.x; i < n4; i += stride) {
    float4 v = ((const float4*)in)[i];
    ushort4 o;
    o.x = f2bf(v.x); o.y = f2bf(v.y); o.z = f2bf(v.z); o.w = f2bf(v.w);
    ((ushort4*)out)[i] = o;
  }
}

// ---------- GEMM staging: A[128][32] + B[128][32] tiles, 16B/lane ----------
__device__ __forceinline__ void stage_ab(const unsigned short* __restrict__ A,
                                         const unsigned short* __restrict__ B,
                                         int K, int bm0, int bn0, int k0,
                                         unsigned short* As, unsigned short* Bs,
                                         int tid) {
#pragma unroll
  for (int i = 0; i < 2; ++i) {
    int e   = (i * 256 + tid) * 8;
    int row = e >> 5;
    int kk  = e & 31;
    async16(A + (size_t)(bm0 + row) * K + (size_t)(k0 + kk), As + e);
    async16(B + (size_t)(bn0 + row) * K + (size_t)(k0 + kk), Bs + e);
  }
}

// ---------- shared GEMM core: C[128x128] tile, double-buffered staging ----------
__device__ __forceinline__ void gemm_core(const unsigned short* __restrict__ A,
                                          const unsigned short* __restrict__ B,
                                          int K, int bm0, int bn0,
                                          unsigned short (*As)[128 * 32],
                                          unsigned short (*Bs)[128 * 32],
                                          f32x4 acc[4][4]) {
  const int tid  = threadIdx.x;
  const int lane = tid & 63;
  const int w    = tid >> 6;
  const int wr   = w >> 1, wc = w & 1;
  const int lrow = lane & 15, lkg = lane >> 4;

  stage_ab(A, B, K, bm0, bn0, 0, As[0], Bs[0], tid);
  __syncthreads();   // DMA(0) drained

  for (int k0 = 0; k0 < K; k0 += 32) {
    const int cur = (k0 >> 5) & 1;
    if (k0 + 32 < K)
      stage_ab(A, B, K, bm0, bn0, k0 + 32, As[cur ^ 1], Bs[cur ^ 1], tid);

    short8 af[4], bf[4];
#pragma unroll
    for (int i = 0; i < 4; ++i) {
      af[i] = *(const short8*)(As[cur] + (wr * 64 + i * 16 + lrow) * 32 + lkg * 8);
      bf[i] = *(const short8*)(Bs[cur] + (wc * 64 + i * 16 + lrow) * 32 + lkg * 8);
    }
#pragma unroll
    for (int i = 0; i < 4; ++i)
#pragma unroll
      for (int j = 0; j < 4; ++j)
        acc[i][j] = __builtin_amdgcn_mfma_f32_16x16x32_bf16(af[i], bf[j], acc[i][j], 0, 0, 0);

    __syncthreads();   // drains stage(k+1); all waves done reading buf[cur]
  }
}

// ---------- fused QKV projection ----------
__global__ __launch_bounds__(256)
void qkv_gemm_k(const unsigned short* __restrict__ xb,
                const unsigned short* __restrict__ wqb,
                const unsigned short* __restrict__ wkb,
                const unsigned short* __restrict__ wvb,
                const float* __restrict__ bq, const float* __restrict__ bk,
                const float* __restrict__ bv,
                unsigned short* __restrict__ Qb, unsigned short* __restrict__ Kb,
                unsigned short* __restrict__ Vtb) {
  __shared__ __align__(16) unsigned short As[2][128 * 32];
  __shared__ __align__(16) unsigned short Bs[2][128 * 32];
  const int z = blockIdx.z;
  const unsigned short* B = (z == 0) ? wqb : (z == 1) ? wkb : wvb;
  const float* bias       = (z == 0) ? bq  : (z == 1) ? bk  : bv;
  const int bm0 = blockIdx.y * 128, bn0 = blockIdx.x * 128;

  f32x4 acc[4][4] = {};
  gemm_core(xb, B, DIM, bm0, bn0, As, Bs, acc);

  const int lane = threadIdx.x & 63;
  const int w = threadIdx.x >> 6, wr = w >> 1, wc = w & 1;
  unsigned short* out01 = (z == 0) ? Qb : Kb;
#pragma unroll
  for (int i = 0; i < 4; ++i)
#pragma unroll
    for (int j = 0; j < 4; ++j)
#pragma unroll
      for (int r = 0; r < 4; ++r) {
        int mg = bm0 + wr * 64 + i * 16 + (lane >> 4) * 4 + r;
        int ng = bn0 + wc * 64 + j * 16 + (lane & 15);
        float v = acc[i][j][r] + bias[ng];
        int bb = mg >> 11, s = mg & 2047, h = ng >> 6, d = ng & 63;
        int bh = bb * HEADS + h;
        if (z < 2)
          out01[((size_t)bh * SEQ + s) * HD + d] = f2bf(v);   // [b,h,s,d]
        else
          Vtb[((size_t)bh * HD + d) * SEQ + s] = f2bf(v);     // [b,h,d,s]
      }
}

// ---------- output projection (fp32 out + bias) ----------
__global__ __launch_bounds__(256)
void out_gemm_k(const unsigned short* __restrict__ Ob,
                const unsigned short* __restrict__ wob,
                const float* __restrict__ bo, float* __restrict__ out) {
  __shared__ __align__(16) unsigned short As[2][128 * 32];
  __shared__ __align__(16) unsigned short Bs[2][128 * 32];
  const int bm0 = blockIdx.y * 128, bn0 = blockIdx.x * 128;

  f32x4 acc[4][4] = {};
  gemm_core(Ob, wob, DIM, bm0, bn0, As, Bs, acc);

  const int lane = threadIdx.x & 63;
  const int w = threadIdx.x >> 6, wr = w >> 1, wc = w & 1;
#pragma unroll
  for (int i = 0; i < 4; ++i)
#pragma unroll
    for (int j = 0; j < 4; ++j)
#pragma unroll
      for (int r = 0; r < 4; ++r) {
        int mg = bm0 + wr * 64 + i * 16 + (lane >> 4) * 4 + r;
        int ng = bn0 + wc * 64 + j * 16 + (lane & 15);
        out[(size_t)mg * DIM + ng] = acc[i][j][r] + bo[ng];
      }
}

// ---------- attention: KVBLK=128 staging (round-4-verified swizzles) ----------
__device__ __forceinline__ void stage_kv128(const unsigned short* __restrict__ kbase,
                                            const unsigned short* __restrict__ vbase,
                                            int k0, unsigned short* KsB,
                                            unsigned short* VsB, int tid) {
#pragma unroll
  for (int j = 0; j < 4; ++j) {
    const int c    = j * 256 + tid;   // K[128 k][64 d]: 1024 x 16B
    const int row  = c >> 3;
    const int colb = (c & 7) << 4;
    const int srcb = colb ^ ((row & 7) << 4);
    async16(kbase + (size_t)(k0 + row) * HD + (srcb >> 1), KsB + c * 8);
  }
#pragma unroll
  for (int j = 0; j < 4; ++j) {
    const int c    = j * 256 + tid;   // V[64 d][128 k]: 1024 x 16B
    const int d    = c >> 4;
    const int colb = (c & 15) << 4;
    const int srcb = colb ^ ((d & 7) << 4);
    async16(vbase + (size_t)d * SEQ + k0 + (srcb >> 1), VsB + c * 8);
  }
}

// ---------- flash attention: single-Q block, double-buffered KVBLK=128 ----------
// grid (32 bh, 32 y) x 256 threads. qb = 31-y, x-fastest => LPT; at 80 KB LDS
// only 2 blocks/CU are resident, so the dispatch queue provides DYNAMIC
// backfill load balancing (long blocks start first, short ones fill gaps).
// Halved iteration count (nk = ceil((qb+1)/2)) halves per-k-element barrier +
// vmcnt-drain overhead vs KVBLK=64.
__global__ __launch_bounds__(256)
void attn_k(const unsigned short* __restrict__ Q,
            const unsigned short* __restrict__ Kp,
            const unsigned short* __restrict__ Vt,
            const int* __restrict__ pm,
            unsigned short* __restrict__ O) {
  __shared__ __align__(16) unsigned short Ks[2][128 * 64];
  __shared__ __align__(16) unsigned short Vs[2][64 * 128];
  __shared__ __align__(16) unsigned short plds[4][16 * 128];

  const int tid  = threadIdx.x;
  const int lane = tid & 63;
  const int w    = tid >> 6;
  const int lc = lane & 15, lg = lane >> 4;
  const int qb = 31 - blockIdx.y;          // LPT: longest first
  const int bh = blockIdx.x;
  const int b  = bh >> 4, h = bh & 15;

  const size_t base = (size_t)bh * SEQ * HD;
  const unsigned short* kbase = Kp + base;
  const unsigned short* vbase = Vt + (size_t)bh * HD * SEQ;
  const int* pmb = pm + b * SEQ;
  char* pb = (char*)&plds[w][0];
  const int swp = (lc & 7) << 4;

  const int qrow0 = qb * 64 + w * 16;
  const int qrow  = qrow0 + lc;

  short8 qa[2];
  {
    const unsigned short* qp = Q + base + (size_t)qrow * HD + lg * 8;
    qa[0] = *(const short8*)(qp);
    qa[1] = *(const short8*)(qp + 32);
  }

  f32x4 oacc[4] = {};
  float mrow = -1e30f, lsum = 0.f;

  const int nk = (qb + 2) >> 1;            // 128-wide k-tiles to the diagonal

  stage_kv128(kbase, vbase, 0, Ks[0], Vs[0], tid);

  // per-wave padding-mask scan (no LDS flag; overlaps DMA(0))
  int ok = 1;
  for (int i = lane; i < SEQ / 4; i += 64) {
    int4 v = ((const int4*)pmb)[i];
    ok &= (v.x != 0) & (v.y != 0) & (v.z != 0) & (v.w != 0);
  }
  const bool allones = __all(ok);
  __syncthreads();   // DMA(0) drained

  for (int kt = 0; kt < nk; ++kt) {
    const int cur = kt & 1;
    const int k0 = kt * 128;
    if (kt + 1 < nk)
      stage_kv128(kbase, vbase, k0 + 128, Ks[cur ^ 1], Vs[cur ^ 1], tid);

    // ---- QK^T swapped: mfma(K, Q) -> lane holds S[q=qrow][k-slice] ----
    f32x4 s[8];
    const char* kbuf = (const char*)Ks[cur];
    __builtin_amdgcn_s_setprio(1);
#pragma unroll
    for (int t = 0; t < 8; ++t) {
      const int row = t * 16 + lc;
      const int swk = (row & 7) << 4;
      const char* kr = kbuf + row * 128;
      short8 kb0 = *(const short8*)(kr + ((lg * 16) ^ swk));
      short8 kb1 = *(const short8*)(kr + ((lg * 16 + 64) ^ swk));
      f32x4 z = {};
      z = __builtin_amdgcn_mfma_f32_16x16x32_bf16(kb0, qa[0], z, 0, 0, 0);
      z = __builtin_amdgcn_mfma_f32_16x16x32_bf16(kb1, qa[1], z, 0, 0, 0);
#pragma unroll
      for (int r = 0; r < 4; ++r) s[t][r] = z[r] * SCALE2;   // log2-domain
    }
    __builtin_amdgcn_s_setprio(0);

    // ---- masks: full work only if padding has zeros; else last tile only ----
    if (!allones) {
#pragma unroll
      for (int t = 0; t < 8; ++t) {
        const int kr0 = k0 + t * 16;
        int4 pmv = *(const int4*)(pmb + kr0 + lg * 4);
#pragma unroll
        for (int r = 0; r < 4; ++r) {
          const int kidx = kr0 + lg * 4 + r;
          if (kidx > qrow || (&pmv.x)[r] == 0) s[t][r] = NEGV;
        }
      }
    } else if (kt == nk - 1) {
#pragma unroll
      for (int t = 0; t < 8; ++t)
#pragma unroll
        for (int r = 0; r < 4; ++r) {
          const int kidx = k0 + t * 16 + lg * 4 + r;
          if (kidx > qrow) s[t][r] = NEGV;
        }
    }

    // ---- online softmax: shuffle-free common path (defer-max) ----
    float mx = -1e30f;
#pragma unroll
    for (int t = 0; t < 8; ++t)
      mx = fmaxf(mx, fmaxf(fmaxf(s[t][0], s[t][1]), fmaxf(s[t][2], s[t][3])));
    if (!__all(mx <= mrow + THR2)) {       // rare: true row max + rescale
      mx = fmaxf(mx, __shfl_xor(mx, 16, 64));
      mx = fmaxf(mx, __shfl_xor(mx, 32, 64));
      const float mnew = fmaxf(mrow, mx);
      const float sc = exp2f(mrow - mnew);
      lsum *= sc;
      mrow = mnew;
      const float s0 = __shfl(sc, lg * 4 + 0, 64);
      const float s1 = __shfl(sc, lg * 4 + 1, 64);
      const float s2 = __shfl(sc, lg * 4 + 2, 64);
      const float s3 = __shfl(sc, lg * 4 + 3, 64);
#pragma unroll
      for (int t = 0; t < 4; ++t) {
        oacc[t][0] *= s0; oacc[t][1] *= s1; oacc[t][2] *= s2; oacc[t][3] *= s3;
      }
    }
    float sum = 0.f;
#pragma unroll
    for (int t = 0; t < 8; ++t)
#pragma unroll
      for (int r = 0; r < 4; ++r) {
        const float p = exp2f(s[t][r] - mrow);
        s[t][r] = p;
        sum += p;
      }
    lsum += sum;                           // per-lane partial; reduced at end

    // ---- P -> per-wave LDS (bf16, swizzled), wave-synchronous ----
#pragma unroll
    for (int t = 0; t < 8; ++t) {
      short4 pk;
      pk.x = (short)f2bf(s[t][0]); pk.y = (short)f2bf(s[t][1]);
      pk.z = (short)f2bf(s[t][2]); pk.w = (short)f2bf(s[t][3]);
      const int colb = (t * 16 + lg * 4) * 2;
      *(short4*)(pb + lc * 256 + (colb ^ swp)) = pk;
    }
    short8 pa[4];
#pragma unroll
    for (int ks = 0; ks < 4; ++ks)
      pa[ks] = *(const short8*)(pb + lc * 256 + (((ks * 32 + lg * 8) * 2) ^ swp));

    // ---- PV: O += P @ V, V fragments from swizzled LDS ----
    const char* vbuf = (const char*)Vs[cur];
    __builtin_amdgcn_s_setprio(1);
#pragma unroll
    for (int t = 0; t < 4; ++t) {
      const int d = t * 16 + lc;
      const int swv = (d & 7) << 4;
      const char* vr = vbuf + d * 256;
#pragma unroll
      for (int ks = 0; ks < 4; ++ks) {
        short8 vv = *(const short8*)(vr + ((ks * 64 + lg * 16) ^ swv));
        oacc[t] = __builtin_amdgcn_mfma_f32_16x16x32_bf16(pa[ks], vv, oacc[t], 0, 0, 0);
      }
    }
    __builtin_amdgcn_s_setprio(0);

    __syncthreads();   // drains stage(kt+1) DMA; all waves done with buf[cur]
  }

  // ---- epilogue: reduce partial lsum across the 4 row-copies, store ----
  lsum += __shfl_xor(lsum, 16, 64);
  lsum += __shfl_xor(lsum, 32, 64);
  const float l0 = __shfl(lsum, lg * 4 + 0, 64);
  const float l1 = __shfl(lsum, lg * 4 + 1, 64);
  const float l2 = __shfl(lsum, lg * 4 + 2, 64);
  const float l3 = __shfl(lsum, lg * 4 + 3, 64);
  const float i0 = 1.f / l0, i1 = 1.f / l1, i2 = 1.f / l2, i3 = 1.f / l3;
#pragma unroll
  for (int t = 0; t < 4; ++t) {
    const size_t o0 = ((size_t)(b * SEQ + qrow0 + lg * 4)) * DIM + h * HD + t * 16 + lc;
    O[o0]           = f2bf(oacc[t][0] * i0);
    O[o0 + DIM]     = f2bf(oacc[t][1] * i1);
    O[o0 + 2 * DIM] = f2bf(oacc[t][2] * i2);
    O[o0 + 3 * DIM] = f2bf(oacc[t][3] * i3);
  }
}

extern "C" void kernel_launch(void* const* d_in, const int* in_sizes, int n_in,
                              void* d_out, int out_size, void* d_ws, size_t ws_size,
                              hipStream_t stream) {
  const float* x  = (const float*)d_in[0];
  const int*   pm = (const int*)d_in[1];
  const float* Wq = (const float*)d_in[3];
  const float* bq = (const float*)d_in[4];
  const float* Wk = (const float*)d_in[5];
  const float* bk = (const float*)d_in[6];
  const float* Wv = (const float*)d_in[7];
  const float* bv = (const float*)d_in[8];
  const float* Wo = (const float*)d_in[9];
  const float* bo = (const float*)d_in[10];

  const size_t NX = (size_t)4096 * 1024;
  const size_t NW = (size_t)1024 * 1024;

  unsigned short* ws  = (unsigned short*)d_ws;
  unsigned short* xb  = ws;
  unsigned short* wqb = xb + NX;
  unsigned short* wkb = wqb + NW;
  unsigned short* wvb = wkb + NW;
  unsigned short* wob = wvb + NW;
  unsigned short* Qb  = wob + NW;
  unsigned short* Kb  = Qb + NX;
  unsigned short* Vtb = Kb + NX;
  unsigned short* Ob  = xb;   // alias: x no longer needed after QKV GEMM

  cast_all_k<<<dim3(1024, 5), dim3(256), 0, stream>>>(
      x, Wq, Wk, Wv, Wo, xb, wqb, wkb, wvb, wob,
      (int)(NX / 4), (int)(NW / 4));

  qkv_gemm_k<<<dim3(8, 32, 3), dim3(256), 0, stream>>>(xb, wqb, wkb, wvb,
                                                       bq, bk, bv, Qb, Kb, Vtb);

  attn_k<<<dim3(32, 32), dim3(256), 0, stream>>>(Qb, Kb, Vtb, pm, Ob);

  out_gemm_k<<<dim3(8, 32), dim3(256), 0, stream>>>(Ob, wob, bo, (float*)d_out);
}

// Round 14
// 129.888 us; speedup vs baseline: 1.1799x; 1.0120x over previous
//
#include <hip/hip_runtime.h>
#include <hip/hip_bf16.h>
#include <stdint.h>

#define SEQ 2048
#define DIM 1024
#define HEADS 16
#define HD 64
#define NEGV (-1e9f)
#define SCALE2 0.18033688011112042f   // 0.125 * log2(e)
#define THR2 11.541560327111707f      // 8 * log2(e)

typedef __attribute__((ext_vector_type(8))) short short8;
typedef __attribute__((ext_vector_type(4))) float f32x4;

__device__ __forceinline__ unsigned short f2bf(float f) {
  __hip_bfloat16 h = __float2bfloat16(f);
  union { __hip_bfloat16 h; unsigned short u; } cv;
  cv.h = h;
  return cv.u;
}

__device__ __forceinline__ float bf2f(unsigned short u) {
  union { unsigned int i; float f; } cv;
  cv.i = ((unsigned int)u) << 16;
  return cv.f;
}

__device__ __forceinline__ void async16(const void* g, void* l) {
  __builtin_amdgcn_global_load_lds(
      (const __attribute__((address_space(1))) unsigned int*)g,
      (__attribute__((address_space(3))) unsigned int*)l, 16, 0, 0);
}

// ---------- merged fp32 -> bf16 cast: y=0 -> x, y=1..4 -> weights ----------
__global__ void cast_all_k(const float* __restrict__ x,
                           const float* __restrict__ w0, const float* __restrict__ w1,
                           const float* __restrict__ w2, const float* __restrict__ w3,
                           unsigned short* __restrict__ xo,
                           unsigned short* __restrict__ o0, unsigned short* __restrict__ o1,
                           unsigned short* __restrict__ o2, unsigned short* __restrict__ o3,
                           int nx4, int nw4) {
  const int seg = blockIdx.y;
  const float* in = (seg == 0) ? x : (seg == 1) ? w0 : (seg == 2) ? w1
                   : (seg == 3) ? w2 : w3;
  unsigned short* out = (seg == 0) ? xo : (seg == 1) ? o0 : (seg == 2) ? o1
                       : (seg == 3) ? o2 : o3;
  const int n4 = (seg == 0) ? nx4 : nw4;
  int stride = gridDim.x * blockDim.x;
  for (int i = blockIdx.x * blockDim.x + threadIdx.x; i < n4; i += stride) {
    float4 v = ((const float4*)in)[i];
    ushort4 o;
    o.x = f2bf(v.x); o.y = f2bf(v.y); o.z = f2bf(v.z); o.w = f2bf(v.w);
    ((ushort4*)out)[i] = o;
  }
}

// ---------- GEMM staging: A[128][32] + B[128][32] tiles, 16B/lane ----------
__device__ __forceinline__ void stage_ab(const unsigned short* __restrict__ A,
                                         const unsigned short* __restrict__ B,
                                         int K, int bm0, int bn0, int k0,
                                         unsigned short* As, unsigned short* Bs,
                                         int tid) {
#pragma unroll
  for (int i = 0; i < 2; ++i) {
    int e   = (i * 256 + tid) * 8;
    int row = e >> 5;
    int kk  = e & 31;
    async16(A + (size_t)(bm0 + row) * K + (size_t)(k0 + kk), As + e);
    async16(B + (size_t)(bn0 + row) * K + (size_t)(k0 + kk), Bs + e);
  }
}

// ---------- shared GEMM core: C[128x128] tile, double-buffered staging ----------
__device__ __forceinline__ void gemm_core(const unsigned short* __restrict__ A,
                                          const unsigned short* __restrict__ B,
                                          int K, int bm0, int bn0,
                                          unsigned short (*As)[128 * 32],
                                          unsigned short (*Bs)[128 * 32],
                                          f32x4 acc[4][4]) {
  const int tid  = threadIdx.x;
  const int lane = tid & 63;
  const int w    = tid >> 6;
  const int wr   = w >> 1, wc = w & 1;
  const int lrow = lane & 15, lkg = lane >> 4;

  stage_ab(A, B, K, bm0, bn0, 0, As[0], Bs[0], tid);
  __syncthreads();   // DMA(0) drained

  for (int k0 = 0; k0 < K; k0 += 32) {
    const int cur = (k0 >> 5) & 1;
    if (k0 + 32 < K)
      stage_ab(A, B, K, bm0, bn0, k0 + 32, As[cur ^ 1], Bs[cur ^ 1], tid);

    short8 af[4], bf[4];
#pragma unroll
    for (int i = 0; i < 4; ++i) {
      af[i] = *(const short8*)(As[cur] + (wr * 64 + i * 16 + lrow) * 32 + lkg * 8);
      bf[i] = *(const short8*)(Bs[cur] + (wc * 64 + i * 16 + lrow) * 32 + lkg * 8);
    }
#pragma unroll
    for (int i = 0; i < 4; ++i)
#pragma unroll
      for (int j = 0; j < 4; ++j)
        acc[i][j] = __builtin_amdgcn_mfma_f32_16x16x32_bf16(af[i], bf[j], acc[i][j], 0, 0, 0);

    __syncthreads();   // drains stage(k+1); all waves done reading buf[cur]
  }
}

// ---------- fused QKV projection ----------
__global__ __launch_bounds__(256)
void qkv_gemm_k(const unsigned short* __restrict__ xb,
                const unsigned short* __restrict__ wqb,
                const unsigned short* __restrict__ wkb,
                const unsigned short* __restrict__ wvb,
                const float* __restrict__ bq, const float* __restrict__ bk,
                const float* __restrict__ bv,
                unsigned short* __restrict__ Qb, unsigned short* __restrict__ Kb,
                unsigned short* __restrict__ Vtb) {
  __shared__ __align__(16) unsigned short As[2][128 * 32];
  __shared__ __align__(16) unsigned short Bs[2][128 * 32];
  const int z = blockIdx.z;
  const unsigned short* B = (z == 0) ? wqb : (z == 1) ? wkb : wvb;
  const float* bias       = (z == 0) ? bq  : (z == 1) ? bk  : bv;
  const int bm0 = blockIdx.y * 128, bn0 = blockIdx.x * 128;

  f32x4 acc[4][4] = {};
  gemm_core(xb, B, DIM, bm0, bn0, As, Bs, acc);

  const int lane = threadIdx.x & 63;
  const int w = threadIdx.x >> 6, wr = w >> 1, wc = w & 1;
  unsigned short* out01 = (z == 0) ? Qb : Kb;
#pragma unroll
  for (int i = 0; i < 4; ++i)
#pragma unroll
    for (int j = 0; j < 4; ++j)
#pragma unroll
      for (int r = 0; r < 4; ++r) {
        int mg = bm0 + wr * 64 + i * 16 + (lane >> 4) * 4 + r;
        int ng = bn0 + wc * 64 + j * 16 + (lane & 15);
        float v = acc[i][j][r] + bias[ng];
        int bb = mg >> 11, s = mg & 2047, h = ng >> 6, d = ng & 63;
        int bh = bb * HEADS + h;
        if (z < 2)
          out01[((size_t)bh * SEQ + s) * HD + d] = f2bf(v);   // [b,h,s,d]
        else
          Vtb[((size_t)bh * HD + d) * SEQ + s] = f2bf(v);     // [b,h,d,s]
      }
}

// ---------- output projection (fp32 out + bias) ----------
__global__ __launch_bounds__(256)
void out_gemm_k(const unsigned short* __restrict__ Ob,
                const unsigned short* __restrict__ wob,
                const float* __restrict__ bo, float* __restrict__ out) {
  __shared__ __align__(16) unsigned short As[2][128 * 32];
  __shared__ __align__(16) unsigned short Bs[2][128 * 32];
  const int bm0 = blockIdx.y * 128, bn0 = blockIdx.x * 128;

  f32x4 acc[4][4] = {};
  gemm_core(Ob, wob, DIM, bm0, bn0, As, Bs, acc);

  const int lane = threadIdx.x & 63;
  const int w = threadIdx.x >> 6, wr = w >> 1, wc = w & 1;
#pragma unroll
  for (int i = 0; i < 4; ++i)
#pragma unroll
    for (int j = 0; j < 4; ++j)
#pragma unroll
      for (int r = 0; r < 4; ++r) {
        int mg = bm0 + wr * 64 + i * 16 + (lane >> 4) * 4 + r;
        int ng = bn0 + wc * 64 + j * 16 + (lane & 15);
        out[(size_t)mg * DIM + ng] = acc[i][j][r] + bo[ng];
      }
}

// ---------- attention: KVBLK=64 staging, swizzled source ----------
__device__ __forceinline__ void stage_kv64(const unsigned short* __restrict__ kbase,
                                           const unsigned short* __restrict__ vbase,
                                           int k0, unsigned short* KsB,
                                           unsigned short* VsB, int tid) {
#pragma unroll
  for (int j = 0; j < 2; ++j) {
    const int c    = j * 256 + tid;   // 512 chunks of 16B: K[64][64]
    const int row  = c >> 3;
    const int colb = (c & 7) << 4;
    const int srcb = colb ^ ((row & 7) << 4);
    async16(kbase + (size_t)(k0 + row) * HD + (srcb >> 1), KsB + c * 8);
  }
#pragma unroll
  for (int j = 0; j < 2; ++j) {
    const int c    = j * 256 + tid;   // V[64 d][64 k]
    const int d    = c >> 3;
    const int colb = (c & 7) << 4;
    const int srcb = colb ^ ((d & 7) << 4);
    async16(vbase + (size_t)d * SEQ + k0 + (srcb >> 1), VsB + c * 8);
  }
}

// ---------- flash attention with split long blocks (flash-decode) ----------
// grid (32 bh, 48 y) x 256 threads, x-fastest (LPT):
//   y in [0,32):  SPLIT halves of qb = 31-(y>>1); half = y&1; k-range
//                 [0,hk) or [hk,nk), hk = (qb+1)>>1  (qb 31..16, <=16 tiles)
//   y in [32,48): unsplit qb = 47-y (15..0)
// Split halves write unnormalized bf16 O + fp32 (m,l) partials into scratch
// (the d_out region, unused until out_gemm); attn_combine_k merges pairs.
// Longest serial chain: 32 -> 16 tile-iterations.
__global__ __launch_bounds__(256)
void attn_k(const unsigned short* __restrict__ Q,
            const unsigned short* __restrict__ Kp,
            const unsigned short* __restrict__ Vt,
            const int* __restrict__ pm,
            unsigned short* __restrict__ O,
            unsigned short* __restrict__ pO,
            float* __restrict__ pml) {
  __shared__ __align__(16) unsigned short Ks[2][64 * 64];
  __shared__ __align__(16) unsigned short Vs[2][64 * 64];
  __shared__ __align__(16) unsigned short plds[4][16 * 64];

  const int tid  = threadIdx.x;
  const int lane = tid & 63;
  const int w    = tid >> 6;
  const int lc = lane & 15, lg = lane >> 4;
  const int y = blockIdx.y;
  const int bh = blockIdx.x;
  const int b  = bh >> 4, h = bh & 15;

  int qb, ks, ke;
  bool split;
  if (y < 32) {
    split = true;
    qb = 31 - (y >> 1);
    const int nk = qb + 1, hk = nk >> 1;
    ks = (y & 1) ? hk : 0;
    ke = (y & 1) ? nk : hk;
  } else {
    split = false;
    qb = 47 - y;
    ks = 0;
    ke = qb + 1;
  }

  const size_t base = (size_t)bh * SEQ * HD;
  const unsigned short* kbase = Kp + base;
  const unsigned short* vbase = Vt + (size_t)bh * HD * SEQ;
  const int* pmb = pm + b * SEQ;
  char* pb = (char*)&plds[w][0];
  const int swp = (lc & 7) << 4;

  const int qrow0 = qb * 64 + w * 16;
  const int qrow  = qrow0 + lc;

  short8 qa[2];
  {
    const unsigned short* qp = Q + base + (size_t)qrow * HD + lg * 8;
    qa[0] = *(const short8*)(qp);
    qa[1] = *(const short8*)(qp + 32);
  }

  f32x4 oacc[4] = {};
  float mrow = -1e30f, lsum = 0.f;
  const int niter = ke - ks;

  stage_kv64(kbase, vbase, ks * 64, Ks[0], Vs[0], tid);

  // per-wave padding-mask scan (overlaps DMA(0))
  int ok = 1;
  for (int i = lane; i < SEQ / 4; i += 64) {
    int4 v = ((const int4*)pmb)[i];
    ok &= (v.x != 0) & (v.y != 0) & (v.z != 0) & (v.w != 0);
  }
  const bool allones = __all(ok);
  __syncthreads();   // DMA(0) drained

  for (int i = 0; i < niter; ++i) {
    const int cur = i & 1;
    const int kt = ks + i;
    const int k0 = kt * 64;
    if (i + 1 < niter)
      stage_kv64(kbase, vbase, k0 + 64, Ks[cur ^ 1], Vs[cur ^ 1], tid);

    // ---- QK^T swapped: mfma(K, Q) -> lane holds S[q=qrow][k-slice] ----
    f32x4 s[4];
    const char* kbuf = (const char*)Ks[cur];
    __builtin_amdgcn_s_setprio(1);
#pragma unroll
    for (int t = 0; t < 4; ++t) {
      const int row = t * 16 + lc;
      const int swk = (row & 7) << 4;
      const char* kr = kbuf + row * 128;
      short8 kb0 = *(const short8*)(kr + ((lg * 16) ^ swk));
      short8 kb1 = *(const short8*)(kr + ((lg * 16 + 64) ^ swk));
      f32x4 z = {};
      z = __builtin_amdgcn_mfma_f32_16x16x32_bf16(kb0, qa[0], z, 0, 0, 0);
      z = __builtin_amdgcn_mfma_f32_16x16x32_bf16(kb1, qa[1], z, 0, 0, 0);
#pragma unroll
      for (int r = 0; r < 4; ++r) s[t][r] = z[r] * SCALE2;   // log2-domain
    }
    __builtin_amdgcn_s_setprio(0);

    // ---- masks: full work only if padding has zeros; else diagonal only ----
    if (!allones) {
#pragma unroll
      for (int t = 0; t < 4; ++t) {
        const int kr0 = k0 + t * 16;
        int4 pmv = *(const int4*)(pmb + kr0 + lg * 4);
#pragma unroll
        for (int r = 0; r < 4; ++r) {
          const int kidx = kr0 + lg * 4 + r;
          if (kidx > qrow || (&pmv.x)[r] == 0) s[t][r] = NEGV;
        }
      }
    } else if (kt == qb) {
#pragma unroll
      for (int t = 0; t < 4; ++t)
#pragma unroll
        for (int r = 0; r < 4; ++r) {
          const int kidx = k0 + t * 16 + lg * 4 + r;
          if (kidx > qrow) s[t][r] = NEGV;
        }
    }

    // ---- online softmax: shuffle-free common path (defer-max) ----
    float mx = -1e30f;
#pragma unroll
    for (int t = 0; t < 4; ++t)
      mx = fmaxf(mx, fmaxf(fmaxf(s[t][0], s[t][1]), fmaxf(s[t][2], s[t][3])));
    if (!__all(mx <= mrow + THR2)) {       // rare: true row max + rescale
      mx = fmaxf(mx, __shfl_xor(mx, 16, 64));
      mx = fmaxf(mx, __shfl_xor(mx, 32, 64));
      const float mnew = fmaxf(mrow, mx);
      const float sc = exp2f(mrow - mnew);
      lsum *= sc;
      mrow = mnew;
      const float s0 = __shfl(sc, lg * 4 + 0, 64);
      const float s1 = __shfl(sc, lg * 4 + 1, 64);
      const float s2 = __shfl(sc, lg * 4 + 2, 64);
      const float s3 = __shfl(sc, lg * 4 + 3, 64);
#pragma unroll
      for (int t = 0; t < 4; ++t) {
        oacc[t][0] *= s0; oacc[t][1] *= s1; oacc[t][2] *= s2; oacc[t][3] *= s3;
      }
    }
    float sum = 0.f;
#pragma unroll
    for (int t = 0; t < 4; ++t)
#pragma unroll
      for (int r = 0; r < 4; ++r) {
        const float p = exp2f(s[t][r] - mrow);
        s[t][r] = p;
        sum += p;
      }
    lsum += sum;                           // per-lane partial; reduced at end

    // ---- P -> per-wave LDS (bf16, swizzled), wave-synchronous ----
#pragma unroll
    for (int t = 0; t < 4; ++t) {
      short4 pk;
      pk.x = (short)f2bf(s[t][0]); pk.y = (short)f2bf(s[t][1]);
      pk.z = (short)f2bf(s[t][2]); pk.w = (short)f2bf(s[t][3]);
      const int colb = (t * 16 + lg * 4) * 2;
      *(short4*)(pb + lc * 128 + (colb ^ swp)) = pk;
    }
    short8 pa[2];
#pragma unroll
    for (int ks2 = 0; ks2 < 2; ++ks2)
      pa[ks2] = *(const short8*)(pb + lc * 128 + (((ks2 * 32 + lg * 8) * 2) ^ swp));

    // ---- PV: O += P @ V, V fragments from swizzled LDS ----
    const char* vbuf = (const char*)Vs[cur];
    __builtin_amdgcn_s_setprio(1);
#pragma unroll
    for (int t = 0; t < 4; ++t) {
      const int d = t * 16 + lc;
      const int swv = (d & 7) << 4;
      const char* vr = vbuf + d * 128;
#pragma unroll
      for (int ks2 = 0; ks2 < 2; ++ks2) {
        short8 vv = *(const short8*)(vr + ((ks2 * 64 + lg * 16) ^ swv));
        oacc[t] = __builtin_amdgcn_mfma_f32_16x16x32_bf16(pa[ks2], vv, oacc[t], 0, 0, 0);
      }
    }
    __builtin_amdgcn_s_setprio(0);

    __syncthreads();   // drains stage(kt+1) DMA; all waves done with buf[cur]
  }

  // ---- epilogue ----
  lsum += __shfl_xor(lsum, 16, 64);
  lsum += __shfl_xor(lsum, 32, 64);
  if (!split) {
    const float l0 = __shfl(lsum, lg * 4 + 0, 64);
    const float l1 = __shfl(lsum, lg * 4 + 1, 64);
    const float l2 = __shfl(lsum, lg * 4 + 2, 64);
    const float l3 = __shfl(lsum, lg * 4 + 3, 64);
    const float i0 = 1.f / l0, i1 = 1.f / l1, i2 = 1.f / l2, i3 = 1.f / l3;
#pragma unroll
    for (int t = 0; t < 4; ++t) {
      const size_t o0 = ((size_t)(b * SEQ + qrow0 + lg * 4)) * DIM + h * HD + t * 16 + lc;
      O[o0]           = f2bf(oacc[t][0] * i0);
      O[o0 + DIM]     = f2bf(oacc[t][1] * i1);
      O[o0 + 2 * DIM] = f2bf(oacc[t][2] * i2);
      O[o0 + 3 * DIM] = f2bf(oacc[t][3] * i3);
    }
  } else {
    const int p = ((qb - 16) * 32 + bh) * 2 + (y & 1);
    if (lg == 0) {
      pml[((size_t)p * 64 + w * 16 + lc) * 2 + 0] = mrow;
      pml[((size_t)p * 64 + w * 16 + lc) * 2 + 1] = lsum;
    }
#pragma unroll
    for (int t = 0; t < 4; ++t)
#pragma unroll
      for (int r = 0; r < 4; ++r)
        pO[((size_t)p * 64 + w * 16 + lg * 4 + r) * 64 + t * 16 + lc] =
            f2bf(oacc[t][r]);
  }
}

// ---------- combine split halves: Ob[qb*64+r] = (OA*aA + OB*aB) / l ----------
__global__ __launch_bounds__(256)
void attn_combine_k(const unsigned short* __restrict__ pO,
                    const float* __restrict__ pml,
                    unsigned short* __restrict__ Ob) {
  const int bh = blockIdx.x;         // 32
  const int qb = 16 + blockIdx.y;    // 16..31
  const int b = bh >> 4, h = bh & 15;
  const int pbase = ((qb - 16) * 32 + bh) * 2;
  const int r  = threadIdx.x >> 2;        // 0..63
  const int cb = (threadIdx.x & 3) * 16;  // 0,16,32,48

  const float mA = pml[((size_t)(pbase + 0) * 64 + r) * 2 + 0];
  const float lA = pml[((size_t)(pbase + 0) * 64 + r) * 2 + 1];
  const float mB = pml[((size_t)(pbase + 1) * 64 + r) * 2 + 0];
  const float lB = pml[((size_t)(pbase + 1) * 64 + r) * 2 + 1];
  const float mN = fmaxf(mA, mB);
  const float aA = exp2f(mA - mN), aB = exp2f(mB - mN);
  const float il = 1.f / (lA * aA + lB * aB);

  const unsigned short* rowA = pO + ((size_t)(pbase + 0) * 64 + r) * 64 + cb;
  const unsigned short* rowB = pO + ((size_t)(pbase + 1) * 64 + r) * 64 + cb;
  unsigned short* orow = Ob + ((size_t)(b * SEQ + qb * 64 + r)) * DIM + h * HD + cb;

  short8 a0 = *(const short8*)(rowA);
  short8 a1 = *(const short8*)(rowA + 8);
  short8 b0 = *(const short8*)(rowB);
  short8 b1 = *(const short8*)(rowB + 8);
  short8 o0, o1;
#pragma unroll
  for (int j = 0; j < 8; ++j) {
    o0[j] = (short)f2bf((bf2f((unsigned short)a0[j]) * aA +
                         bf2f((unsigned short)b0[j]) * aB) * il);
    o1[j] = (short)f2bf((bf2f((unsigned short)a1[j]) * aA +
                         bf2f((unsigned short)b1[j]) * aB) * il);
  }
  *(short8*)(orow)     = o0;
  *(short8*)(orow + 8) = o1;
}

extern "C" void kernel_launch(void* const* d_in, const int* in_sizes, int n_in,
                              void* d_out, int out_size, void* d_ws, size_t ws_size,
                              hipStream_t stream) {
  const float* x  = (const float*)d_in[0];
  const int*   pm = (const int*)d_in[1];
  const float* Wq = (const float*)d_in[3];
  const float* bq = (const float*)d_in[4];
  const float* Wk = (const float*)d_in[5];
  const float* bk = (const float*)d_in[6];
  const float* Wv = (const float*)d_in[7];
  const float* bv = (const float*)d_in[8];
  const float* Wo = (const float*)d_in[9];
  const float* bo = (const float*)d_in[10];

  const size_t NX = (size_t)4096 * 1024;
  const size_t NW = (size_t)1024 * 1024;

  unsigned short* ws  = (unsigned short*)d_ws;
  unsigned short* xb  = ws;
  unsigned short* wqb = xb + NX;
  unsigned short* wkb = wqb + NW;
  unsigned short* wvb = wkb + NW;
  unsigned short* wob = wvb + NW;
  unsigned short* Qb  = wob + NW;
  unsigned short* Kb  = Qb + NX;
  unsigned short* Vtb = Kb + NX;
  unsigned short* Ob  = xb;   // alias: x no longer needed after QKV GEMM

  // scratch for split-attention partials lives in d_out (overwritten by
  // out_gemm at the end): 1024 x 64 x 64 bf16 (8.39 MB) + 1024 x 64 x 2 f32
  unsigned short* pO  = (unsigned short*)d_out;
  float*          pml = (float*)(pO + (size_t)1024 * 64 * 64);

  cast_all_k<<<dim3(1024, 5), dim3(256), 0, stream>>>(
      x, Wq, Wk, Wv, Wo, xb, wqb, wkb, wvb, wob,
      (int)(NX / 4), (int)(NW / 4));

  qkv_gemm_k<<<dim3(8, 32, 3), dim3(256), 0, stream>>>(xb, wqb, wkb, wvb,
                                                       bq, bk, bv, Qb, Kb, Vtb);

  attn_k<<<dim3(32, 48), dim3(256), 0, stream>>>(Qb, Kb, Vtb, pm, Ob, pO, pml);

  attn_combine_k<<<dim3(32, 16), dim3(256), 0, stream>>>(pO, pml, Ob);

  out_gemm_k<<<dim3(8, 32), dim3(256), 0, stream>>>(Ob, wob, bo, (float*)d_out);
}

// Round 15
// 120.664 us; speedup vs baseline: 1.2701x; 1.0764x over previous
//
#include <hip/hip_runtime.h>
#include <hip/hip_bf16.h>
#include <stdint.h>

#define SEQ 2048
#define DIM 1024
#define HEADS 16
#define HD 64
#define NEGV (-1e9f)
#define SCALE2 0.18033688011112042f   // 0.125 * log2(e), folded into Q
#define THR2 11.541560327111707f      // 8 * log2(e)

typedef __attribute__((ext_vector_type(8))) short short8;
typedef __attribute__((ext_vector_type(4))) float f32x4;

__device__ __forceinline__ unsigned short f2bf(float f) {
  __hip_bfloat16 h = __float2bfloat16(f);
  union { __hip_bfloat16 h; unsigned short u; } cv;
  cv.h = h;
  return cv.u;
}

__device__ __forceinline__ void async16(const void* g, void* l) {
  __builtin_amdgcn_global_load_lds(
      (const __attribute__((address_space(1))) unsigned int*)g,
      (__attribute__((address_space(3))) unsigned int*)l, 16, 0, 0);
}

// ---------- merged fp32 -> bf16 cast: y=0 -> x, y=1..4 -> weights ----------
__global__ void cast_all_k(const float* __restrict__ x,
                           const float* __restrict__ w0, const float* __restrict__ w1,
                           const float* __restrict__ w2, const float* __restrict__ w3,
                           unsigned short* __restrict__ xo,
                           unsigned short* __restrict__ o0, unsigned short* __restrict__ o1,
                           unsigned short* __restrict__ o2, unsigned short* __restrict__ o3,
                           int nx4, int nw4) {
  const int seg = blockIdx.y;
  const float* in = (seg == 0) ? x : (seg == 1) ? w0 : (seg == 2) ? w1
                   : (seg == 3) ? w2 : w3;
  unsigned short* out = (seg == 0) ? xo : (seg == 1) ? o0 : (seg == 2) ? o1
                       : (seg == 3) ? o2 : o3;
  const int n4 = (seg == 0) ? nx4 : nw4;
  int stride = gridDim.x * blockDim.x;
  for (int i = blockIdx.x * blockDim.x + threadIdx.x; i < n4; i += stride) {
    float4 v = ((const float4*)in)[i];
    ushort4 o;
    o.x = f2bf(v.x); o.y = f2bf(v.y); o.z = f2bf(v.z); o.w = f2bf(v.w);
    ((ushort4*)out)[i] = o;
  }
}

// ---------- GEMM staging: A[128][32] + B[128][32] tiles, 16B/lane ----------
__device__ __forceinline__ void stage_ab(const unsigned short* __restrict__ A,
                                         const unsigned short* __restrict__ B,
                                         int K, int bm0, int bn0, int k0,
                                         unsigned short* As, unsigned short* Bs,
                                         int tid) {
#pragma unroll
  for (int i = 0; i < 2; ++i) {
    int e   = (i * 256 + tid) * 8;
    int row = e >> 5;
    int kk  = e & 31;
    async16(A + (size_t)(bm0 + row) * K + (size_t)(k0 + kk), As + e);
    async16(B + (size_t)(bn0 + row) * K + (size_t)(k0 + kk), Bs + e);
  }
}

// ---------- shared GEMM core: C[128x128] tile, double-buffered staging ----------
__device__ __forceinline__ void gemm_core(const unsigned short* __restrict__ A,
                                          const unsigned short* __restrict__ B,
                                          int K, int bm0, int bn0,
                                          unsigned short (*As)[128 * 32],
                                          unsigned short (*Bs)[128 * 32],
                                          f32x4 acc[4][4]) {
  const int tid  = threadIdx.x;
  const int lane = tid & 63;
  const int w    = tid >> 6;
  const int wr   = w >> 1, wc = w & 1;
  const int lrow = lane & 15, lkg = lane >> 4;

  stage_ab(A, B, K, bm0, bn0, 0, As[0], Bs[0], tid);
  __syncthreads();   // DMA(0) drained

  for (int k0 = 0; k0 < K; k0 += 32) {
    const int cur = (k0 >> 5) & 1;
    if (k0 + 32 < K)
      stage_ab(A, B, K, bm0, bn0, k0 + 32, As[cur ^ 1], Bs[cur ^ 1], tid);

    short8 af[4], bf[4];
#pragma unroll
    for (int i = 0; i < 4; ++i) {
      af[i] = *(const short8*)(As[cur] + (wr * 64 + i * 16 + lrow) * 32 + lkg * 8);
      bf[i] = *(const short8*)(Bs[cur] + (wc * 64 + i * 16 + lrow) * 32 + lkg * 8);
    }
#pragma unroll
    for (int i = 0; i < 4; ++i)
#pragma unroll
      for (int j = 0; j < 4; ++j)
        acc[i][j] = __builtin_amdgcn_mfma_f32_16x16x32_bf16(af[i], bf[j], acc[i][j], 0, 0, 0);

    __syncthreads();   // drains stage(k+1); all waves done reading buf[cur]
  }
}

// ---------- fused QKV projection (Q pre-scaled by SCALE2 for attn) ----------
__global__ __launch_bounds__(256)
void qkv_gemm_k(const unsigned short* __restrict__ xb,
                const unsigned short* __restrict__ wqb,
                const unsigned short* __restrict__ wkb,
                const unsigned short* __restrict__ wvb,
                const float* __restrict__ bq, const float* __restrict__ bk,
                const float* __restrict__ bv,
                unsigned short* __restrict__ Qb, unsigned short* __restrict__ Kb,
                unsigned short* __restrict__ Vtb) {
  __shared__ __align__(16) unsigned short As[2][128 * 32];
  __shared__ __align__(16) unsigned short Bs[2][128 * 32];
  const int z = blockIdx.z;
  const unsigned short* B = (z == 0) ? wqb : (z == 1) ? wkb : wvb;
  const float* bias       = (z == 0) ? bq  : (z == 1) ? bk  : bv;
  const int bm0 = blockIdx.y * 128, bn0 = blockIdx.x * 128;

  f32x4 acc[4][4] = {};
  gemm_core(xb, B, DIM, bm0, bn0, As, Bs, acc);

  const int lane = threadIdx.x & 63;
  const int w = threadIdx.x >> 6, wr = w >> 1, wc = w & 1;
  unsigned short* out01 = (z == 0) ? Qb : Kb;
  const float oscale = (z == 0) ? SCALE2 : 1.0f;
#pragma unroll
  for (int i = 0; i < 4; ++i)
#pragma unroll
    for (int j = 0; j < 4; ++j)
#pragma unroll
      for (int r = 0; r < 4; ++r) {
        int mg = bm0 + wr * 64 + i * 16 + (lane >> 4) * 4 + r;
        int ng = bn0 + wc * 64 + j * 16 + (lane & 15);
        float v = (acc[i][j][r] + bias[ng]) * oscale;
        int bb = mg >> 11, s = mg & 2047, h = ng >> 6, d = ng & 63;
        int bh = bb * HEADS + h;
        if (z < 2)
          out01[((size_t)bh * SEQ + s) * HD + d] = f2bf(v);   // [b,h,s,d]
        else
          Vtb[((size_t)bh * HD + d) * SEQ + s] = f2bf(v);     // [b,h,d,s]
      }
}

// ---------- output projection (fp32 out + bias) ----------
__global__ __launch_bounds__(256)
void out_gemm_k(const unsigned short* __restrict__ Ob,
                const unsigned short* __restrict__ wob,
                const float* __restrict__ bo, float* __restrict__ out) {
  __shared__ __align__(16) unsigned short As[2][128 * 32];
  __shared__ __align__(16) unsigned short Bs[2][128 * 32];
  const int bm0 = blockIdx.y * 128, bn0 = blockIdx.x * 128;

  f32x4 acc[4][4] = {};
  gemm_core(Ob, wob, DIM, bm0, bn0, As, Bs, acc);

  const int lane = threadIdx.x & 63;
  const int w = threadIdx.x >> 6, wr = w >> 1, wc = w & 1;
#pragma unroll
  for (int i = 0; i < 4; ++i)
#pragma unroll
    for (int j = 0; j < 4; ++j)
#pragma unroll
      for (int r = 0; r < 4; ++r) {
        int mg = bm0 + wr * 64 + i * 16 + (lane >> 4) * 4 + r;
        int ng = bn0 + wc * 64 + j * 16 + (lane & 15);
        out[(size_t)mg * DIM + ng] = acc[i][j][r] + bo[ng];
      }
}

// ---------- attention: KVBLK=64 staging, swizzled source ----------
__device__ __forceinline__ void stage_kv64(const unsigned short* __restrict__ kbase,
                                           const unsigned short* __restrict__ vbase,
                                           int k0, unsigned short* KsB,
                                           unsigned short* VsB, int tid) {
#pragma unroll
  for (int j = 0; j < 2; ++j) {
    const int c    = j * 256 + tid;   // 512 chunks of 16B: K[64][64]
    const int row  = c >> 3;
    const int colb = (c & 7) << 4;
    const int srcb = colb ^ ((row & 7) << 4);
    async16(kbase + (size_t)(k0 + row) * HD + (srcb >> 1), KsB + c * 8);
  }
#pragma unroll
  for (int j = 0; j < 2; ++j) {
    const int c    = j * 256 + tid;   // V[64 d][64 k]
    const int d    = c >> 3;
    const int colb = (c & 7) << 4;
    const int srcb = colb ^ ((d & 7) << 4);
    async16(vbase + (size_t)d * SEQ + k0 + (srcb >> 1), VsB + c * 8);
  }
}

// ---------- flash attention: single-Q block, double-buffered KVBLK=64 ----------
// grid (32 bh, 32 qbpos) x 256 threads. qb = 31-blockIdx.y, x-fastest =>
// globally longest-first (LPT); 1024 blocks at 4/CU give dynamic backfill.
// LDS = 2*8K (K) + 2*8K (V) + 8K (P) = 40960 B. Softmax in exp2 domain with
// Q pre-scaled; shuffle-free common path (defer-max); per-lane partial lsum.
__global__ __launch_bounds__(256)
void attn_k(const unsigned short* __restrict__ Q,
            const unsigned short* __restrict__ Kp,
            const unsigned short* __restrict__ Vt,
            const int* __restrict__ pm,
            unsigned short* __restrict__ O) {
  __shared__ __align__(16) unsigned short Ks[2][64 * 64];
  __shared__ __align__(16) unsigned short Vs[2][64 * 64];
  __shared__ __align__(16) unsigned short plds[4][16 * 64];

  const int tid  = threadIdx.x;
  const int lane = tid & 63;
  const int w    = tid >> 6;
  const int lc = lane & 15, lg = lane >> 4;
  const int qb = 31 - blockIdx.y;          // globally longest-first
  const int bh = blockIdx.x;
  const int b  = bh >> 4, h = bh & 15;

  const size_t base = (size_t)bh * SEQ * HD;
  const unsigned short* kbase = Kp + base;
  const unsigned short* vbase = Vt + (size_t)bh * HD * SEQ;
  const int* pmb = pm + b * SEQ;
  char* pb = (char*)&plds[w][0];
  const int swp = (lc & 7) << 4;

  const int qrow0 = qb * 64 + w * 16;
  const int qrow  = qrow0 + lc;

  short8 qa[2];
  {
    const unsigned short* qp = Q + base + (size_t)qrow * HD + lg * 8;
    qa[0] = *(const short8*)(qp);
    qa[1] = *(const short8*)(qp + 32);
  }

  f32x4 oacc[4] = {};
  float mrow = -1e30f, lsum = 0.f;

  const int nk = qb + 1;                   // 64-wide k-tiles to the diagonal

  stage_kv64(kbase, vbase, 0, Ks[0], Vs[0], tid);

  // per-wave padding-mask scan (overlaps DMA(0); no LDS flag)
  int ok = 1;
  for (int i = lane; i < SEQ / 4; i += 64) {
    int4 v = ((const int4*)pmb)[i];
    ok &= (v.x != 0) & (v.y != 0) & (v.z != 0) & (v.w != 0);
  }
  const bool allones = __all(ok);
  __syncthreads();   // DMA(0) drained

  for (int kt = 0; kt < nk; ++kt) {
    const int cur = kt & 1;
    const int k0 = kt * 64;
    if (kt + 1 < nk)
      stage_kv64(kbase, vbase, k0 + 64, Ks[cur ^ 1], Vs[cur ^ 1], tid);

    // ---- QK^T swapped: mfma(K, Q) -> lane holds S[q=qrow][k-slice];
    //      Q was pre-scaled by 0.125*log2(e) so z is already log2-domain ----
    f32x4 s[4];
    const char* kbuf = (const char*)Ks[cur];
    __builtin_amdgcn_s_setprio(1);
#pragma unroll
    for (int t = 0; t < 4; ++t) {
      const int row = t * 16 + lc;
      const int swk = (row & 7) << 4;
      const char* kr = kbuf + row * 128;
      short8 kb0 = *(const short8*)(kr + ((lg * 16) ^ swk));
      short8 kb1 = *(const short8*)(kr + ((lg * 16 + 64) ^ swk));
      f32x4 z = {};
      z = __builtin_amdgcn_mfma_f32_16x16x32_bf16(kb0, qa[0], z, 0, 0, 0);
      z = __builtin_amdgcn_mfma_f32_16x16x32_bf16(kb1, qa[1], z, 0, 0, 0);
      s[t] = z;
    }
    __builtin_amdgcn_s_setprio(0);

    // ---- masks: full work only if padding has zeros; else diagonal only ----
    if (!allones) {
#pragma unroll
      for (int t = 0; t < 4; ++t) {
        const int kr0 = k0 + t * 16;
        int4 pmv = *(const int4*)(pmb + kr0 + lg * 4);
#pragma unroll
        for (int r = 0; r < 4; ++r) {
          const int kidx = kr0 + lg * 4 + r;
          if (kidx > qrow || (&pmv.x)[r] == 0) s[t][r] = NEGV;
        }
      }
    } else if (kt == qb) {
#pragma unroll
      for (int t = 0; t < 4; ++t)
#pragma unroll
        for (int r = 0; r < 4; ++r) {
          const int kidx = k0 + t * 16 + lg * 4 + r;
          if (kidx > qrow) s[t][r] = NEGV;
        }
    }

    // ---- online softmax: shuffle-free common path (defer-max) ----
    float mx = -1e30f;
#pragma unroll
    for (int t = 0; t < 4; ++t)
      mx = fmaxf(mx, fmaxf(fmaxf(s[t][0], s[t][1]), fmaxf(s[t][2], s[t][3])));
    if (!__all(mx <= mrow + THR2)) {       // rare: true row max + rescale
      mx = fmaxf(mx, __shfl_xor(mx, 16, 64));
      mx = fmaxf(mx, __shfl_xor(mx, 32, 64));
      const float mnew = fmaxf(mrow, mx);
      const float sc = exp2f(mrow - mnew);
      lsum *= sc;
      mrow = mnew;
      const float s0 = __shfl(sc, lg * 4 + 0, 64);
      const float s1 = __shfl(sc, lg * 4 + 1, 64);
      const float s2 = __shfl(sc, lg * 4 + 2, 64);
      const float s3 = __shfl(sc, lg * 4 + 3, 64);
#pragma unroll
      for (int t = 0; t < 4; ++t) {
        oacc[t][0] *= s0; oacc[t][1] *= s1; oacc[t][2] *= s2; oacc[t][3] *= s3;
      }
    }
    // tree-form partial sums: 4 independent accumulators, short dep chain
    float ps[4];
#pragma unroll
    for (int t = 0; t < 4; ++t) {
      const float p0 = exp2f(s[t][0] - mrow);
      const float p1 = exp2f(s[t][1] - mrow);
      const float p2 = exp2f(s[t][2] - mrow);
      const float p3 = exp2f(s[t][3] - mrow);
      s[t][0] = p0; s[t][1] = p1; s[t][2] = p2; s[t][3] = p3;
      ps[t] = (p0 + p1) + (p2 + p3);
    }
    lsum += (ps[0] + ps[1]) + (ps[2] + ps[3]);   // per-lane partial

    // ---- P -> per-wave LDS (bf16, swizzled), wave-synchronous ----
#pragma unroll
    for (int t = 0; t < 4; ++t) {
      short4 pk;
      pk.x = (short)f2bf(s[t][0]); pk.y = (short)f2bf(s[t][1]);
      pk.z = (short)f2bf(s[t][2]); pk.w = (short)f2bf(s[t][3]);
      const int colb = (t * 16 + lg * 4) * 2;
      *(short4*)(pb + lc * 128 + (colb ^ swp)) = pk;
    }
    short8 pa[2];
#pragma unroll
    for (int ks = 0; ks < 2; ++ks)
      pa[ks] = *(const short8*)(pb + lc * 128 + (((ks * 32 + lg * 8) * 2) ^ swp));

    // ---- PV: O += P @ V, V fragments from swizzled LDS ----
    const char* vbuf = (const char*)Vs[cur];
    __builtin_amdgcn_s_setprio(1);
#pragma unroll
    for (int t = 0; t < 4; ++t) {
      const int d = t * 16 + lc;
      const int swv = (d & 7) << 4;
      const char* vr = vbuf + d * 128;
#pragma unroll
      for (int ks = 0; ks < 2; ++ks) {
        short8 vv = *(const short8*)(vr + ((ks * 64 + lg * 16) ^ swv));
        oacc[t] = __builtin_amdgcn_mfma_f32_16x16x32_bf16(pa[ks], vv, oacc[t], 0, 0, 0);
      }
    }
    __builtin_amdgcn_s_setprio(0);

    __syncthreads();   // drains stage(kt+1) DMA; all waves done with buf[cur]
  }

  // ---- epilogue: reduce partial lsum across the 4 row-copies, store ----
  lsum += __shfl_xor(lsum, 16, 64);
  lsum += __shfl_xor(lsum, 32, 64);
  const float l0 = __shfl(lsum, lg * 4 + 0, 64);
  const float l1 = __shfl(lsum, lg * 4 + 1, 64);
  const float l2 = __shfl(lsum, lg * 4 + 2, 64);
  const float l3 = __shfl(lsum, lg * 4 + 3, 64);
  const float i0 = 1.f / l0, i1 = 1.f / l1, i2 = 1.f / l2, i3 = 1.f / l3;
#pragma unroll
  for (int t = 0; t < 4; ++t) {
    const size_t o0 = ((size_t)(b * SEQ + qrow0 + lg * 4)) * DIM + h * HD + t * 16 + lc;
    O[o0]           = f2bf(oacc[t][0] * i0);
    O[o0 + DIM]     = f2bf(oacc[t][1] * i1);
    O[o0 + 2 * DIM] = f2bf(oacc[t][2] * i2);
    O[o0 + 3 * DIM] = f2bf(oacc[t][3] * i3);
  }
}

extern "C" void kernel_launch(void* const* d_in, const int* in_sizes, int n_in,
                              void* d_out, int out_size, void* d_ws, size_t ws_size,
                              hipStream_t stream) {
  const float* x  = (const float*)d_in[0];
  const int*   pm = (const int*)d_in[1];
  const float* Wq = (const float*)d_in[3];
  const float* bq = (const float*)d_in[4];
  const float* Wk = (const float*)d_in[5];
  const float* bk = (const float*)d_in[6];
  const float* Wv = (const float*)d_in[7];
  const float* bv = (const float*)d_in[8];
  const float* Wo = (const float*)d_in[9];
  const float* bo = (const float*)d_in[10];

  const size_t NX = (size_t)4096 * 1024;
  const size_t NW = (size_t)1024 * 1024;

  unsigned short* ws  = (unsigned short*)d_ws;
  unsigned short* xb  = ws;
  unsigned short* wqb = xb + NX;
  unsigned short* wkb = wqb + NW;
  unsigned short* wvb = wkb + NW;
  unsigned short* wob = wvb + NW;
  unsigned short* Qb  = wob + NW;
  unsigned short* Kb  = Qb + NX;
  unsigned short* Vtb = Kb + NX;
  unsigned short* Ob  = xb;   // alias: x no longer needed after QKV GEMM

  cast_all_k<<<dim3(1024, 5), dim3(256), 0, stream>>>(
      x, Wq, Wk, Wv, Wo, xb, wqb, wkb, wvb, wob,
      (int)(NX / 4), (int)(NW / 4));

  qkv_gemm_k<<<dim3(8, 32, 3), dim3(256), 0, stream>>>(xb, wqb, wkb, wvb,
                                                       bq, bk, bv, Qb, Kb, Vtb);

  attn_k<<<dim3(32, 32), dim3(256), 0, stream>>>(Qb, Kb, Vtb, pm, Ob);

  out_gemm_k<<<dim3(8, 32), dim3(256), 0, stream>>>(Ob, wob, bo, (float*)d_out);
}